// Round 7
// baseline (321.312 us; speedup 1.0000x reference)
//
#include <hip/hip_runtime.h>
#include <math.h>

// ---------------- problem sizes ----------------
#define NB 4
#define LTOK 4096
#define DM 128
#define DI 256
#define NCH 256    // scan chunks
#define TCH 16     // steps per chunk
#define GSZ 16     // chunks per combine group
#define NG  16     // groups = NCH/GSZ

// ---------------- workspace layout (float offsets) ----------------
// mamba intermediates t-major: [b][t][e]
#define OFF_A2     0u          // A2 table [256d][16n] = -exp(A_log)*log2(e) (4096)
#define OFF_BIAS2  73728u      // folded conv+bn bias [128]
#define OFF_XWT    73856u      // (unused legacy)
#define OFF_YDS    84096u      // gelu output [4][128][64][64]   (2097152)
#define OFF_XPRE   2181248u    // [4][4096][256]; ALIASED: S[b][c][n][d] and yact
#define OFF_Z      6375552u    // [4][4096][256]
#define OFF_XIN    10569856u   // [4][4096][256] f32
#define OFF_BC     14764160u   // [4][4096][32]: 0-15 B, 16-31 C (524288)
#define OFF_DSUM   15288448u   // [4][256c][256d] (262144)
#define OFF_GS     15550592u   // [4][16g][16n][256d] (262144); becomes ginit
#define OFF_GD     15812736u   // [4][16g][256d] (16384)
#define OFF_XT     15829120u   // bf16: x-transpose (k0b/k1); then xin_bf; then delta (in-place)
#define OFF_WBF    17926272u   // bf16 conv weights*bn_inv [128co][9tap][64ci] (36864)
#define OFF_WCMP   17963136u   // bf16 composed xproj weights [288n][256k] (36864)
#define OFF_YACT   OFF_XPRE
// total 18000000 floats = 72.0 MB (< proven 79.9 MB budget)

#define DEV __device__ __forceinline__
#define L2E 1.4426950408889634f

typedef short bh8 __attribute__((ext_vector_type(8)));   // 8 bf16 (4 VGPR)
typedef float f4v __attribute__((ext_vector_type(4)));

DEV float fast_silu(float v) {
  return v * __builtin_amdgcn_rcpf(1.f + __expf(-v));
}

DEV unsigned short f2bf(float f) {                       // round-to-nearest-even
  unsigned int u = __float_as_uint(f);
  u = (u + 0x7FFFu + ((u >> 16) & 1u)) >> 16;
  return (unsigned short)u;
}

DEV float bf2f(unsigned short us) {
  return __uint_as_float((unsigned int)us << 16);
}

// =============== K0: bf16 conv weights; bias; A2 table; composed xproj weights ===============
__global__ __launch_bounds__(256) void k0_prep(
    const float* __restrict__ conv_w, const float* __restrict__ conv_b,
    const float* __restrict__ bn_g, const float* __restrict__ bn_b,
    const float* __restrict__ bn_mean, const float* __restrict__ bn_var,
    const float* __restrict__ xproj_w, const float* __restrict__ A_log,
    const float* __restrict__ dtw, float* __restrict__ ws) {
  int i = blockIdx.x * 256 + threadIdx.x;
  if (i < 73728) {
    // wbf[co][tap][ci] = bf16(conv_w[co][ci][tap] * bn_inv[co])
    int ci = i & 63; int tap = (i >> 6) % 9; int co = i / 576;
    float inv = bn_g[co] * rsqrtf(bn_var[co] + 1e-5f);
    ((unsigned short*)(ws + OFF_WBF))[i] = f2bf(conv_w[co * 576 + ci * 9 + tap] * inv);
  } else if (i < 73856) {
    int co = i - 73728;
    float inv = bn_g[co] * rsqrtf(bn_var[co] + 1e-5f);
    ws[OFF_BIAS2 + co] = (conv_b[co] - bn_mean[co]) * inv + bn_b[co];
  } else if (i < 77952) {
    int j = i - 73856;                                   // j = d*16+n
    ws[OFF_A2 + j] = -__expf(A_log[j]) * L2E;
  } else if (i < 77952 + 73728) {
    // wcomp[n][k]: n<256 -> composed delta weights; n>=256 -> B/C rows
    int j = i - 77952;
    int n = j >> 8, k = j & 255;
    float v;
    if (n < 256) {
      v = 0.f;
#pragma unroll
      for (int r = 0; r < 8; ++r)
        v = fmaf(dtw[n * 8 + r], xproj_w[r * 256 + k], v);
    } else {
      v = xproj_w[(8 + n - 256) * 256 + k];
    }
    ((unsigned short*)(ws + OFF_WCMP))[j] = f2bf(v);
  }
}

// =============== K0b: transpose x -> xt[b][iy][ix][ci] bf16 ===============
__global__ __launch_bounds__(256) void k0b_transpose(
    const float* __restrict__ x, unsigned short* __restrict__ xt) {
  __shared__ float t[64][65];
  const int tid = threadIdx.x;
  const int ixh = blockIdx.x & 1;
  const int iy = (blockIdx.x >> 1) & 127;
  const int b = blockIdx.x >> 8;
  {
    const int ixl = tid & 63, cw = tid >> 6;
#pragma unroll 4
    for (int i = 0; i < 16; ++i) {
      int ci = cw * 16 + i;
      t[ci][ixl] = x[(((size_t)(b * 64 + ci) * 128) + iy) * 128 + ixh * 64 + ixl];
    }
  }
  __syncthreads();
  {
    const int cil = tid & 63, iw = tid >> 6;
    unsigned short* dst = xt + (((size_t)(b * 128 + iy) * 128) + ixh * 64) * 64;
#pragma unroll 4
    for (int i = 0; i < 16; ++i) {
      int ix = iw * 16 + i;
      dst[ix * 64 + cil] = f2bf(t[cil][ix]);
    }
  }
}

// =============== K1: conv3x3 s2 + BN + GELU via bf16 MFMA ===============
__global__ __launch_bounds__(256) void k1_conv_mfma(
    const unsigned short* __restrict__ xt, const unsigned short* __restrict__ wbf,
    const float* __restrict__ bias2, float* __restrict__ yds) {
  const int tid = threadIdx.x;
  const int lane = tid & 63;
  const int w = tid >> 6;
  const int col = lane & 15, quad = lane >> 4;
  const int cohalf = blockIdx.x & 1;
  const int oy = (blockIdx.x >> 1) & 63;
  const int b = blockIdx.x >> 7;
  const int co0 = cohalf * 64 + (w & 1) * 32;
  const int tok0 = (w >> 1) * 32;
  const int iy0 = 2 * oy - 1;
  const bh8 bzero = {};
  f4v acc[2][2];
#pragma unroll
  for (int mt = 0; mt < 2; ++mt)
#pragma unroll
    for (int nt = 0; nt < 2; ++nt) acc[mt][nt] = (f4v){0.f, 0.f, 0.f, 0.f};

  const unsigned short* ap0 = wbf + (size_t)(co0 + col) * 576;
  const unsigned short* ap1 = wbf + (size_t)(co0 + 16 + col) * 576;

  for (int tap = 0; tap < 9; ++tap) {
    const int kh = tap / 3, kw = tap - kh * 3;
    const int iy = iy0 + kh;
    const int ix0 = 2 * (tok0 + col) - 1 + kw;
    const int ix1 = ix0 + 32;
    const unsigned short* xrow = xt + (long)(b * 128 + iy) * 8192;
    const bool ok0 = (iy >= 0) && (ix0 >= 0);
    const bool ok1 = (iy >= 0);
#pragma unroll
    for (int kc = 0; kc < 2; ++kc) {
      const int cib = kc * 32 + quad * 8;
      bh8 a0 = *(const bh8*)&ap0[tap * 64 + cib];
      bh8 a1 = *(const bh8*)&ap1[tap * 64 + cib];
      bh8 b0 = *(const bh8*)&xrow[(long)ix0 * 64 + cib];
      bh8 b1 = *(const bh8*)&xrow[(long)ix1 * 64 + cib];
      if (!ok0) b0 = bzero;
      if (!ok1) b1 = bzero;
      acc[0][0] = __builtin_amdgcn_mfma_f32_16x16x32_bf16(a0, b0, acc[0][0], 0, 0, 0);
      acc[1][0] = __builtin_amdgcn_mfma_f32_16x16x32_bf16(a1, b0, acc[1][0], 0, 0, 0);
      acc[0][1] = __builtin_amdgcn_mfma_f32_16x16x32_bf16(a0, b1, acc[0][1], 0, 0, 0);
      acc[1][1] = __builtin_amdgcn_mfma_f32_16x16x32_bf16(a1, b1, acc[1][1], 0, 0, 0);
    }
  }
#pragma unroll
  for (int mt = 0; mt < 2; ++mt)
#pragma unroll
    for (int nt = 0; nt < 2; ++nt) {
      const int tok = tok0 + nt * 16 + col;
#pragma unroll
      for (int r = 0; r < 4; ++r) {
        const int co = co0 + mt * 16 + quad * 4 + r;
        float v = acc[mt][nt][r] + bias2[co];
        float g = 0.5f * v * (1.f + erff(v * 0.70710678118f));
        yds[(((size_t)(b * 128 + co) * 64) + oy) * 64 + tok] = g;
      }
    }
}

// =============== K2: in_proj GEMM -> t-major xpre, z ===============
__global__ __launch_bounds__(256) void k2_inproj(
    const float* __restrict__ yds, const float* __restrict__ in_w,
    float* __restrict__ xpre, float* __restrict__ z) {
  __shared__ __align__(16) float a_lds[64][68];
  __shared__ __align__(16) float w_lds[64][68];
  const int tid = threadIdx.x;
  const int et = blockIdx.x & 7;
  const int rowid = blockIdx.x >> 3;
  const int oy = rowid & 63, b = rowid >> 6;
  const int t4 = (tid & 15) * 4, e4 = (tid >> 4) * 4;
  float acc[4][4];
#pragma unroll
  for (int i = 0; i < 4; ++i)
#pragma unroll
    for (int j = 0; j < 4; ++j) acc[i][j] = 0.f;

  for (int kc = 0; kc < 2; ++kc) {
    __syncthreads();
    for (int idx = tid; idx < 1024; idx += 256) {
      int k = idx >> 4, tq = idx & 15;
      *(float4*)&a_lds[k][tq * 4] =
          *(const float4*)&yds[(((size_t)(b * 128 + kc * 64 + k) * 64) + oy) * 64 + tq * 4];
    }
    for (int idx = tid; idx < 1024; idx += 256) {
      int j = idx >> 4, kq = idx & 15;
      float4 v = *(const float4*)&in_w[(size_t)(et * 64 + j) * 128 + kc * 64 + kq * 4];
      w_lds[kq * 4 + 0][j] = v.x; w_lds[kq * 4 + 1][j] = v.y;
      w_lds[kq * 4 + 2][j] = v.z; w_lds[kq * 4 + 3][j] = v.w;
    }
    __syncthreads();
#pragma unroll 8
    for (int k = 0; k < 64; ++k) {
      float4 a4 = *(const float4*)&a_lds[k][t4];
      float4 b4 = *(const float4*)&w_lds[k][e4];
      float av[4] = {a4.x, a4.y, a4.z, a4.w};
      float bv[4] = {b4.x, b4.y, b4.z, b4.w};
#pragma unroll
      for (int i = 0; i < 4; ++i)
#pragma unroll
        for (int j = 0; j < 4; ++j) acc[i][j] = fmaf(av[i], bv[j], acc[i][j]);
    }
  }
  const int e0 = et * 64 + e4;
#pragma unroll
  for (int i = 0; i < 4; ++i) {
    int t = oy * 64 + t4 + i;
    float4 v = make_float4(acc[i][0], acc[i][1], acc[i][2], acc[i][3]);
    float* dst = (e0 < 256) ? (xpre + ((size_t)(b * 4096 + t)) * 256 + e0)
                            : (z + ((size_t)(b * 4096 + t)) * 256 + (e0 - 256));
    *(float4*)dst = v;
  }
}

// =============== K3: depthwise causal conv1d (k=4) + SiLU; f32 + bf16 out ===============
__global__ __launch_bounds__(256) void k3_conv1d_silu(
    const float* __restrict__ xpre, const float* __restrict__ w,
    const float* __restrict__ bvec, float* __restrict__ xin,
    unsigned short* __restrict__ xinbf) {
  int i = blockIdx.x * 256 + threadIdx.x;
  int e4 = (i & 63) * 4;
  int t = (i >> 6) & 4095;
  int b = i >> 18;
  const float* base = xpre + (size_t)b * 4096 * 256;
  float4 zero = make_float4(0.f, 0.f, 0.f, 0.f);
  float4 r0 = (t >= 3) ? *(const float4*)&base[(size_t)(t - 3) * 256 + e4] : zero;
  float4 r1 = (t >= 2) ? *(const float4*)&base[(size_t)(t - 2) * 256 + e4] : zero;
  float4 r2 = (t >= 1) ? *(const float4*)&base[(size_t)(t - 1) * 256 + e4] : zero;
  float4 r3 = *(const float4*)&base[(size_t)t * 256 + e4];
  float4 w0 = *(const float4*)&w[(e4 + 0) * 4];
  float4 w1 = *(const float4*)&w[(e4 + 1) * 4];
  float4 w2 = *(const float4*)&w[(e4 + 2) * 4];
  float4 w3 = *(const float4*)&w[(e4 + 3) * 4];
  float4 bv = *(const float4*)&bvec[e4];
  float o0 = bv.x + w0.x * r0.x + w0.y * r1.x + w0.z * r2.x + w0.w * r3.x;
  float o1 = bv.y + w1.x * r0.y + w1.y * r1.y + w1.z * r2.y + w1.w * r3.y;
  float o2 = bv.z + w2.x * r0.z + w2.y * r1.z + w2.z * r2.z + w2.w * r3.z;
  float o3 = bv.w + w3.x * r0.w + w3.y * r1.w + w3.z * r2.w + w3.w * r3.w;
  float s0 = fast_silu(o0), s1 = fast_silu(o1), s2 = fast_silu(o2), s3 = fast_silu(o3);
  size_t off = ((size_t)b * 4096 + t) * 256 + e4;
  *(float4*)&xin[off] = make_float4(s0, s1, s2, s3);
  unsigned long long p = (unsigned long long)f2bf(s0)
                       | ((unsigned long long)f2bf(s1) << 16)
                       | ((unsigned long long)f2bf(s2) << 32)
                       | ((unsigned long long)f2bf(s3) << 48);
  *(unsigned long long*)&xinbf[off] = p;
}

// =============== K4: composed x_proj/dt_proj via bf16 MFMA -> delta (in-place), bc, dsum ===============
// Block = 64 tokens (4 waves x 16). A preloaded to registers from xinbf; delta
// overwrites xinbf rows of this block (safe: stores after barrier > all A reads).
__global__ __launch_bounds__(256) void k4_mfma(
    const unsigned short* __restrict__ wcomp, const float* __restrict__ dtb,
    unsigned short* xinbf_delta /* in: xin_bf, out: delta (aliased) */,
    float* __restrict__ bc, float* __restrict__ dsum) {
  __shared__ unsigned short ld_delta[64][264];
  __shared__ float ld_bc[64][33];
  const int tid = threadIdx.x;
  const int lane = tid & 63;
  const int w = tid >> 6;
  const int col = lane & 15, quad = lane >> 4;
  const int tt = blockIdx.x & 63, b = blockIdx.x >> 6;
  const int t0 = tt * 64;
  const int tw = t0 + w * 16;

  // A preload: A[m=col][k=quad*8 + 32*kb + j]
  bh8 afrag[8];
  {
    const unsigned short* arow =
        xinbf_delta + (size_t)(b * 4096 + tw + col) * 256 + quad * 8;
#pragma unroll
    for (int kb = 0; kb < 8; ++kb) afrag[kb] = *(const bh8*)&arow[kb * 32];
  }
  f4v acc[18];
#pragma unroll
  for (int i = 0; i < 18; ++i) acc[i] = (f4v){0.f, 0.f, 0.f, 0.f};

  const unsigned short* wb = wcomp + (size_t)col * 256 + quad * 8;
#pragma unroll 2
  for (int kb = 0; kb < 8; ++kb) {
#pragma unroll
    for (int nt = 0; nt < 18; ++nt) {
      bh8 bfrag = *(const bh8*)&wb[(size_t)nt * 4096 + kb * 32];
      acc[nt] = __builtin_amdgcn_mfma_f32_16x16x32_bf16(afrag[kb], bfrag, acc[nt], 0, 0, 0);
    }
  }
  // D layout: token = quad*4+r (M), n = nt*16+col (N)
#pragma unroll
  for (int nt = 0; nt < 16; ++nt) {
    float bias = dtb[nt * 16 + col];
#pragma unroll
    for (int r = 0; r < 4; ++r) {
      float s = acc[nt][r] + bias;
      float dl = fmaxf(s, 0.f) + log1pf(__expf(-fabsf(s)));   // stable softplus
      ld_delta[w * 16 + quad * 4 + r][nt * 16 + col] = f2bf(dl);
    }
  }
#pragma unroll
  for (int nt = 16; nt < 18; ++nt)
#pragma unroll
    for (int r = 0; r < 4; ++r)
      ld_bc[w * 16 + quad * 4 + r][(nt - 16) * 16 + col] = acc[nt][r];
  __syncthreads();   // LDS complete + all waves' A reads done before in-place stores

  // dsum per 16-token chunk (block = 4 chunks); thread = d
  {
    const int d = tid;
#pragma unroll
    for (int cc = 0; cc < 4; ++cc) {
      float ds = 0.f;
#pragma unroll
      for (int i = 0; i < 16; ++i) ds += bf2f(ld_delta[cc * 16 + i][d]);
      dsum[((size_t)b * 256 + tt * 4 + cc) * 256 + d] = ds;
    }
  }
  // delta out (overwrites xin_bf rows of this block)
#pragma unroll 2
  for (int it = 0; it < 16; ++it) {
    int idx = it * 256 + tid;
    int row = idx >> 6, d4 = (idx & 63) * 4;
    unsigned long long pk = *(const unsigned long long*)&ld_delta[row][d4];
    *(unsigned long long*)&xinbf_delta[((size_t)(b * 4096 + t0 + row)) * 256 + d4] = pk;
  }
  // bc out
#pragma unroll
  for (int it = 0; it < 2; ++it) {
    int idx = it * 256 + tid;
    int row = idx >> 3, q = (idx & 7) * 4;
    float4 v = make_float4(ld_bc[row][q], ld_bc[row][q + 1],
                           ld_bc[row][q + 2], ld_bc[row][q + 3]);
    *(float4*)&bc[((size_t)(b * 4096 + t0 + row)) * 32 + q] = v;
  }
}

// =============== K5a: pass 1 -> S[b][c][n][d] chunk-local scan ===============
__global__ __launch_bounds__(256) void k5a_scan1(
    const float* __restrict__ xin, const float* __restrict__ bc,
    const unsigned short* __restrict__ delta, const float* __restrict__ a2tab,
    float* __restrict__ S) {
  __shared__ __align__(16) float bct[TCH * 32];
  const int tid = threadIdx.x;
  const int d = tid;
  const int c = blockIdx.x & (NCH - 1), b = blockIdx.x >> 8;
  const int t0 = c * TCH;
  {
    const float* src = bc + (size_t)(b * 4096 + t0) * 32;
    for (int i = tid; i < TCH * 32; i += 256) bct[i] = src[i];
  }
  float A2[16];
#pragma unroll
  for (int j = 0; j < 4; ++j) {
    float4 a = *(const float4*)&a2tab[d * 16 + j * 4];
    A2[4 * j + 0] = a.x; A2[4 * j + 1] = a.y; A2[4 * j + 2] = a.z; A2[4 * j + 3] = a.w;
  }
  float h[16];
#pragma unroll
  for (int n = 0; n < 16; ++n) h[n] = 0.f;
  const unsigned short* pd = delta + (size_t)(b * 4096 + t0) * 256 + d;
  const float* px = xin + (size_t)(b * 4096 + t0) * 256 + d;
  __syncthreads();
#pragma unroll 4
  for (int i = 0; i < TCH; ++i) {
    float dl = bf2f(pd[(size_t)i * 256]);
    float xv = px[(size_t)i * 256];
    float dlx = dl * xv;
    const float* r = &bct[i * 32];
    float4 B0 = *(const float4*)&r[0];
    float4 B1 = *(const float4*)&r[4];
    float4 B2 = *(const float4*)&r[8];
    float4 B3 = *(const float4*)&r[12];
    float Bv[16] = {B0.x, B0.y, B0.z, B0.w, B1.x, B1.y, B1.z, B1.w,
                    B2.x, B2.y, B2.z, B2.w, B3.x, B3.y, B3.z, B3.w};
#pragma unroll
    for (int n = 0; n < 16; ++n)
      h[n] = fmaf(exp2f(dl * A2[n]), h[n], dlx * Bv[n]);
  }
  const size_t sbase = ((size_t)(b * NCH + c) * 16) * 256 + d;
#pragma unroll
  for (int n = 0; n < 16; ++n) S[sbase + (size_t)n * 256] = h[n];
}

// =============== K5b1: within-group combine (in-place exclusive prefix) ===============
__global__ __launch_bounds__(256) void k5b1_group(
    float* __restrict__ S, const float* __restrict__ dsum,
    const float* __restrict__ a2tab, float* __restrict__ Gs,
    float* __restrict__ Gd) {
  const int d = threadIdx.x;
  const int n = blockIdx.x & 15, g = (blockIdx.x >> 4) & (NG - 1),
            b = blockIdx.x >> 8;
  const float A2 = a2tab[d * 16 + n];
  float h = 0.f, cum = 0.f;
#pragma unroll 4
  for (int c16 = 0; c16 < GSZ; ++c16) {
    int c = g * GSZ + c16;
    size_t si = ((size_t)(b * NCH + c) * 16 + n) * 256 + d;
    float s = S[si];
    float dsv = dsum[((size_t)b * NCH + c) * 256 + d];
    float P = exp2f(A2 * dsv);
    S[si] = h;
    h = fmaf(P, h, s);
    cum += dsv;
  }
  Gs[((size_t)(b * NG + g) * 16 + n) * 256 + d] = h;
  if (n == 0) Gd[((size_t)b * NG + g) * 256 + d] = cum;
}

// =============== K5b2: scan group totals -> ginit in-place over Gs ===============
__global__ __launch_bounds__(256) void k5b2_groupscan(
    float* __restrict__ Gs, const float* __restrict__ Gd,
    const float* __restrict__ a2tab) {
  const int d = threadIdx.x;
  const int n = blockIdx.x & 15, b = blockIdx.x >> 4;
  const float A2 = a2tab[d * 16 + n];
  float h = 0.f;
#pragma unroll
  for (int g = 0; g < NG; ++g) {
    size_t gi = ((size_t)(b * NG + g) * 16 + n) * 256 + d;
    float s = Gs[gi];
    float P = exp2f(A2 * Gd[((size_t)b * NG + g) * 256 + d]);
    Gs[gi] = h;
    h = fmaf(P, h, s);
  }
}

// =============== K5c: pass 2 -> y, fused (+x*Dp)*silu(z) ===============
__global__ __launch_bounds__(256) void k5c_scan2(
    const float* __restrict__ xin, const float* __restrict__ bc,
    const unsigned short* __restrict__ delta, const float* __restrict__ z,
    const float* __restrict__ a2tab, const float* __restrict__ Dp,
    const float* __restrict__ dsum, const float* __restrict__ Gs,
    float* sy) {
  __shared__ __align__(16) float bct[TCH * 32];
  const int tid = threadIdx.x;
  const int d = tid;
  const int c = blockIdx.x & (NCH - 1), b = blockIdx.x >> 8;
  const int t0 = c * TCH;
  {
    const float* src = bc + (size_t)(b * 4096 + t0) * 32;
    for (int i = tid; i < TCH * 32; i += 256) bct[i] = src[i];
  }
  float A2[16];
#pragma unroll
  for (int j = 0; j < 4; ++j) {
    float4 a = *(const float4*)&a2tab[d * 16 + j * 4];
    A2[4 * j + 0] = a.x; A2[4 * j + 1] = a.y; A2[4 * j + 2] = a.z; A2[4 * j + 3] = a.w;
  }
  const float Dpd = Dp[d];
  const int g = c >> 4, c16 = c & 15;
  float dpref = 0.f;
  {
    const float* pds = dsum + ((size_t)b * NCH + g * GSZ) * 256 + d;
    for (int cc = 0; cc < c16; ++cc) dpref += pds[(size_t)cc * 256];
  }
  const size_t sbase = ((size_t)(b * NCH + c) * 16) * 256 + d;
  const size_t gbase = ((size_t)(b * NG + g) * 16) * 256 + d;
  float h[16];
#pragma unroll
  for (int n = 0; n < 16; ++n) {
    float gi = Gs[gbase + (size_t)n * 256];
    float hl = sy[sbase + (size_t)n * 256];
    h[n] = fmaf(exp2f(A2[n] * dpref), gi, hl);
  }
  const size_t base = (size_t)(b * 4096 + t0) * 256 + d;
  const unsigned short* pd = delta + base;
  const float* px = xin + base;
  const float* pz = z + base;
  float* py = sy + base;
  __syncthreads();
#pragma unroll 4
  for (int i = 0; i < TCH; ++i) {
    float dl = bf2f(pd[(size_t)i * 256]);
    float xv = px[(size_t)i * 256];
    float zv = pz[(size_t)i * 256];
    float dlx = dl * xv;
    const float* r = &bct[i * 32];
    float4 B0 = *(const float4*)&r[0];
    float4 B1 = *(const float4*)&r[4];
    float4 B2 = *(const float4*)&r[8];
    float4 B3 = *(const float4*)&r[12];
    float4 C0 = *(const float4*)&r[16];
    float4 C1 = *(const float4*)&r[20];
    float4 C2 = *(const float4*)&r[24];
    float4 C3 = *(const float4*)&r[28];
    float Bv[16] = {B0.x, B0.y, B0.z, B0.w, B1.x, B1.y, B1.z, B1.w,
                    B2.x, B2.y, B2.z, B2.w, B3.x, B3.y, B3.z, B3.w};
    float Cv[16] = {C0.x, C0.y, C0.z, C0.w, C1.x, C1.y, C1.z, C1.w,
                    C2.x, C2.y, C2.z, C2.w, C3.x, C3.y, C3.z, C3.w};
    float y = 0.f;
#pragma unroll
    for (int n = 0; n < 16; ++n) {
      h[n] = fmaf(exp2f(dl * A2[n]), h[n], dlx * Bv[n]);
      y = fmaf(h[n], Cv[n], y);
    }
    py[(size_t)i * 256] = (y + xv * Dpd) * fast_silu(zv);
  }
}

// =============== K6: out_proj GEMM + residual ===============
__global__ __launch_bounds__(256) void k6_outproj(
    const float* __restrict__ yact, const float* __restrict__ out_w,
    const float* __restrict__ yds, float* __restrict__ out) {
  __shared__ __align__(16) float a_lds[64][68];
  __shared__ __align__(16) float w_lds[64][132];
  const int tid = threadIdx.x;
  const int oy = blockIdx.x & 63, b = blockIdx.x >> 6;
  const int t4 = (tid & 15) * 4, c8 = (tid >> 4) * 8;
  float acc[4][8];
#pragma unroll
  for (int i = 0; i < 4; ++i)
#pragma unroll
    for (int j = 0; j < 8; ++j) acc[i][j] = 0.f;

  for (int kc = 0; kc < 4; ++kc) {
    __syncthreads();
    for (int idx = tid; idx < 1024; idx += 256) {
      int tl = idx >> 4; int e4 = (idx & 15) * 4;
      float4 v = *(const float4*)&yact[((size_t)(b * 4096 + oy * 64 + tl)) * 256 + kc * 64 + e4];
      a_lds[e4 + 0][tl] = v.x; a_lds[e4 + 1][tl] = v.y;
      a_lds[e4 + 2][tl] = v.z; a_lds[e4 + 3][tl] = v.w;
    }
    for (int idx = tid; idx < 2048; idx += 256) {
      int cc = idx >> 4, kq = idx & 15;
      float4 v = *(const float4*)&out_w[(size_t)cc * 256 + kc * 64 + kq * 4];
      w_lds[kq * 4 + 0][cc] = v.x; w_lds[kq * 4 + 1][cc] = v.y;
      w_lds[kq * 4 + 2][cc] = v.z; w_lds[kq * 4 + 3][cc] = v.w;
    }
    __syncthreads();
#pragma unroll 4
    for (int k = 0; k < 64; ++k) {
      float4 a4 = *(const float4*)&a_lds[k][t4];
      float4 b0 = *(const float4*)&w_lds[k][c8];
      float4 b1 = *(const float4*)&w_lds[k][c8 + 4];
      float av[4] = {a4.x, a4.y, a4.z, a4.w};
      float bv[8] = {b0.x, b0.y, b0.z, b0.w, b1.x, b1.y, b1.z, b1.w};
#pragma unroll
      for (int i = 0; i < 4; ++i)
#pragma unroll
        for (int j = 0; j < 8; ++j) acc[i][j] = fmaf(av[i], bv[j], acc[i][j]);
    }
  }
#pragma unroll
  for (int j = 0; j < 8; ++j) {
    int cc = c8 + j;
    size_t base = (((size_t)(b * 128 + cc) * 64) + oy) * 64 + t4;
    float4 r = *(const float4*)&yds[base];
    *(float4*)&out[base] = make_float4(acc[0][j] + r.x, acc[1][j] + r.y,
                                       acc[2][j] + r.z, acc[3][j] + r.w);
  }
}

// =============== launch ===============
extern "C" void kernel_launch(void* const* d_in, const int* in_sizes, int n_in,
                              void* d_out, int out_size, void* d_ws, size_t ws_size,
                              hipStream_t stream) {
  (void)in_sizes; (void)n_in; (void)out_size; (void)ws_size;
  const float* x        = (const float*)d_in[0];
  const float* conv_w   = (const float*)d_in[1];
  const float* conv_b   = (const float*)d_in[2];
  const float* bn_g     = (const float*)d_in[3];
  const float* bn_b     = (const float*)d_in[4];
  const float* bn_mean  = (const float*)d_in[5];
  const float* bn_var   = (const float*)d_in[6];
  const float* in_w     = (const float*)d_in[7];
  const float* conv1d_w = (const float*)d_in[8];
  const float* conv1d_b = (const float*)d_in[9];
  const float* xproj_w  = (const float*)d_in[10];
  const float* dtproj_w = (const float*)d_in[11];
  const float* dtproj_b = (const float*)d_in[12];
  const float* A_log    = (const float*)d_in[13];
  const float* Dp       = (const float*)d_in[14];
  const float* out_w    = (const float*)d_in[15];
  float* ws = (float*)d_ws;
  float* out = (float*)d_out;

  k0_prep<<<593, 256, 0, stream>>>(conv_w, conv_b, bn_g, bn_b, bn_mean, bn_var,
                                   xproj_w, A_log, dtproj_w, ws);
  k0b_transpose<<<1024, 256, 0, stream>>>(x, (unsigned short*)(ws + OFF_XT));
  k1_conv_mfma<<<512, 256, 0, stream>>>((const unsigned short*)(ws + OFF_XT),
                                        (const unsigned short*)(ws + OFF_WBF),
                                        ws + OFF_BIAS2, ws + OFF_YDS);
  k2_inproj<<<2048, 256, 0, stream>>>(ws + OFF_YDS, in_w, ws + OFF_XPRE, ws + OFF_Z);
  k3_conv1d_silu<<<4096, 256, 0, stream>>>(ws + OFF_XPRE, conv1d_w, conv1d_b,
                                           ws + OFF_XIN,
                                           (unsigned short*)(ws + OFF_XT));
  k4_mfma<<<256, 256, 0, stream>>>((const unsigned short*)(ws + OFF_WCMP),
                                   dtproj_b, (unsigned short*)(ws + OFF_XT),
                                   ws + OFF_BC, ws + OFF_DSUM);
  k5a_scan1<<<1024, 256, 0, stream>>>(ws + OFF_XIN, ws + OFF_BC,
                                      (const unsigned short*)(ws + OFF_XT),
                                      ws + OFF_A2, ws + OFF_XPRE);
  k5b1_group<<<1024, 256, 0, stream>>>(ws + OFF_XPRE, ws + OFF_DSUM, ws + OFF_A2,
                                       ws + OFF_GS, ws + OFF_GD);
  k5b2_groupscan<<<64, 256, 0, stream>>>(ws + OFF_GS, ws + OFF_GD, ws + OFF_A2);
  k5c_scan2<<<1024, 256, 0, stream>>>(ws + OFF_XIN, ws + OFF_BC,
                                      (const unsigned short*)(ws + OFF_XT),
                                      ws + OFF_Z, ws + OFF_A2, Dp, ws + OFF_DSUM,
                                      ws + OFF_GS, ws + OFF_XPRE);
  k6_outproj<<<256, 256, 0, stream>>>(ws + OFF_YACT, out_w, ws + OFF_YDS, out);
}

// Round 8
// 293.214 us; speedup vs baseline: 1.0958x; 1.0958x over previous
//
#include <hip/hip_runtime.h>
#include <math.h>

// ---------------- problem sizes ----------------
#define NB 4
#define LTOK 4096
#define DM 128
#define DI 256
#define NCH 256    // scan chunks
#define TCH 16     // steps per chunk
#define GSZ 16     // chunks per combine group
#define NG  16     // groups = NCH/GSZ

// ---------------- workspace layout (float offsets) ----------------
// mamba intermediates t-major: [b][t][e]
#define OFF_A2     0u          // A2 table [256d][16n] = -exp(A_log)*log2(e) (4096)
#define OFF_BIAS2  73728u      // folded conv+bn bias [128]
#define OFF_YDS    84096u      // gelu output [4][128][64][64]   (2097152)
#define OFF_XPRE   2181248u    // [4][4096][256]; ALIASED: S[b][c][n][d] and yact
#define OFF_Z      6375552u    // [4][4096][256]
#define OFF_XIN    10569856u   // [4][4096][256] f32
#define OFF_BC     14764160u   // [4][4096][32]: 0-15 B, 16-31 C (524288)
#define OFF_DSUM   15288448u   // [4][256c][256d] (262144)
#define OFF_GS     15550592u   // [4][16g][16n][256d] (262144); becomes ginit
#define OFF_GD     15812736u   // [4][16g][256d] (16384)
#define OFF_XT     15829120u   // bf16: x-transpose (k0b/k1); then xin_bf; then delta (in-place)
#define OFF_WBF    17926272u   // bf16 conv weights*bn_inv [128co][9tap][64ci] (36864)
#define OFF_WCMP   17963136u   // bf16 composed xproj weights [320n][256k] (40960 fl; n>=288 zero)
#define OFF_YACT   OFF_XPRE
// total 18004096 floats = 72.0 MB (< proven 79.9 MB budget)

#define DEV __device__ __forceinline__
#define L2E 1.4426950408889634f

typedef short bh8 __attribute__((ext_vector_type(8)));   // 8 bf16 (4 VGPR)
typedef float f4v __attribute__((ext_vector_type(4)));

DEV float fast_silu(float v) {
  return v * __builtin_amdgcn_rcpf(1.f + __expf(-v));
}

DEV unsigned short f2bf(float f) {                       // round-to-nearest-even
  unsigned int u = __float_as_uint(f);
  u = (u + 0x7FFFu + ((u >> 16) & 1u)) >> 16;
  return (unsigned short)u;
}

DEV float bf2f(unsigned short us) {
  return __uint_as_float((unsigned int)us << 16);
}

// =============== K0: bf16 conv weights; bias; A2 table; composed xproj weights ===============
__global__ __launch_bounds__(256) void k0_prep(
    const float* __restrict__ conv_w, const float* __restrict__ conv_b,
    const float* __restrict__ bn_g, const float* __restrict__ bn_b,
    const float* __restrict__ bn_mean, const float* __restrict__ bn_var,
    const float* __restrict__ xproj_w, const float* __restrict__ A_log,
    const float* __restrict__ dtw, float* __restrict__ ws) {
  int i = blockIdx.x * 256 + threadIdx.x;
  if (i < 73728) {
    // wbf[co][tap][ci] = bf16(conv_w[co][ci][tap] * bn_inv[co])
    int ci = i & 63; int tap = (i >> 6) % 9; int co = i / 576;
    float inv = bn_g[co] * rsqrtf(bn_var[co] + 1e-5f);
    ((unsigned short*)(ws + OFF_WBF))[i] = f2bf(conv_w[co * 576 + ci * 9 + tap] * inv);
  } else if (i < 73856) {
    int co = i - 73728;
    float inv = bn_g[co] * rsqrtf(bn_var[co] + 1e-5f);
    ws[OFF_BIAS2 + co] = (conv_b[co] - bn_mean[co]) * inv + bn_b[co];
  } else if (i < 77952) {
    int j = i - 73856;                                   // j = d*16+n
    ws[OFF_A2 + j] = -__expf(A_log[j]) * L2E;
  } else if (i < 77952 + 81920) {
    // wcomp[n][k], n in [0,320): n<256 composed delta weights; 256..287 B/C; else 0
    int j = i - 77952;
    int n = j >> 8, k = j & 255;
    float v = 0.f;
    if (n < 256) {
#pragma unroll
      for (int r = 0; r < 8; ++r)
        v = fmaf(dtw[n * 8 + r], xproj_w[r * 256 + k], v);
    } else if (n < 288) {
      v = xproj_w[(8 + n - 256) * 256 + k];
    }
    ((unsigned short*)(ws + OFF_WCMP))[j] = f2bf(v);
  }
}

// =============== K0b: transpose x -> xt[b][iy][ix][ci] bf16 ===============
__global__ __launch_bounds__(256) void k0b_transpose(
    const float* __restrict__ x, unsigned short* __restrict__ xt) {
  __shared__ float t[64][65];
  const int tid = threadIdx.x;
  const int ixh = blockIdx.x & 1;
  const int iy = (blockIdx.x >> 1) & 127;
  const int b = blockIdx.x >> 8;
  {
    const int ixl = tid & 63, cw = tid >> 6;
#pragma unroll 4
    for (int i = 0; i < 16; ++i) {
      int ci = cw * 16 + i;
      t[ci][ixl] = x[(((size_t)(b * 64 + ci) * 128) + iy) * 128 + ixh * 64 + ixl];
    }
  }
  __syncthreads();
  {
    const int cil = tid & 63, iw = tid >> 6;
    unsigned short* dst = xt + (((size_t)(b * 128 + iy) * 128) + ixh * 64) * 64;
#pragma unroll 4
    for (int i = 0; i < 16; ++i) {
      int ix = iw * 16 + i;
      dst[ix * 64 + cil] = f2bf(t[cil][ix]);
    }
  }
}

// =============== K1: conv3x3 s2 + BN + GELU via bf16 MFMA ===============
__global__ __launch_bounds__(256) void k1_conv_mfma(
    const unsigned short* __restrict__ xt, const unsigned short* __restrict__ wbf,
    const float* __restrict__ bias2, float* __restrict__ yds) {
  const int tid = threadIdx.x;
  const int lane = tid & 63;
  const int w = tid >> 6;
  const int col = lane & 15, quad = lane >> 4;
  const int cohalf = blockIdx.x & 1;
  const int oy = (blockIdx.x >> 1) & 63;
  const int b = blockIdx.x >> 7;
  const int co0 = cohalf * 64 + (w & 1) * 32;
  const int tok0 = (w >> 1) * 32;
  const int iy0 = 2 * oy - 1;
  const bh8 bzero = {};
  f4v acc[2][2];
#pragma unroll
  for (int mt = 0; mt < 2; ++mt)
#pragma unroll
    for (int nt = 0; nt < 2; ++nt) acc[mt][nt] = (f4v){0.f, 0.f, 0.f, 0.f};

  const unsigned short* ap0 = wbf + (size_t)(co0 + col) * 576;
  const unsigned short* ap1 = wbf + (size_t)(co0 + 16 + col) * 576;

  for (int tap = 0; tap < 9; ++tap) {
    const int kh = tap / 3, kw = tap - kh * 3;
    const int iy = iy0 + kh;
    const int ix0 = 2 * (tok0 + col) - 1 + kw;
    const int ix1 = ix0 + 32;
    const unsigned short* xrow = xt + (long)(b * 128 + iy) * 8192;
    const bool ok0 = (iy >= 0) && (ix0 >= 0);
    const bool ok1 = (iy >= 0);
#pragma unroll
    for (int kc = 0; kc < 2; ++kc) {
      const int cib = kc * 32 + quad * 8;
      bh8 a0 = *(const bh8*)&ap0[tap * 64 + cib];
      bh8 a1 = *(const bh8*)&ap1[tap * 64 + cib];
      bh8 b0 = *(const bh8*)&xrow[(long)ix0 * 64 + cib];
      bh8 b1 = *(const bh8*)&xrow[(long)ix1 * 64 + cib];
      if (!ok0) b0 = bzero;
      if (!ok1) b1 = bzero;
      acc[0][0] = __builtin_amdgcn_mfma_f32_16x16x32_bf16(a0, b0, acc[0][0], 0, 0, 0);
      acc[1][0] = __builtin_amdgcn_mfma_f32_16x16x32_bf16(a1, b0, acc[1][0], 0, 0, 0);
      acc[0][1] = __builtin_amdgcn_mfma_f32_16x16x32_bf16(a0, b1, acc[0][1], 0, 0, 0);
      acc[1][1] = __builtin_amdgcn_mfma_f32_16x16x32_bf16(a1, b1, acc[1][1], 0, 0, 0);
    }
  }
#pragma unroll
  for (int mt = 0; mt < 2; ++mt)
#pragma unroll
    for (int nt = 0; nt < 2; ++nt) {
      const int tok = tok0 + nt * 16 + col;
#pragma unroll
      for (int r = 0; r < 4; ++r) {
        const int co = co0 + mt * 16 + quad * 4 + r;
        float v = acc[mt][nt][r] + bias2[co];
        float g = 0.5f * v * (1.f + erff(v * 0.70710678118f));
        yds[(((size_t)(b * 128 + co) * 64) + oy) * 64 + tok] = g;
      }
    }
}

// =============== K2: in_proj GEMM -> t-major xpre, z ===============
__global__ __launch_bounds__(256) void k2_inproj(
    const float* __restrict__ yds, const float* __restrict__ in_w,
    float* __restrict__ xpre, float* __restrict__ z) {
  __shared__ __align__(16) float a_lds[64][68];
  __shared__ __align__(16) float w_lds[64][68];
  const int tid = threadIdx.x;
  const int et = blockIdx.x & 7;
  const int rowid = blockIdx.x >> 3;
  const int oy = rowid & 63, b = rowid >> 6;
  const int t4 = (tid & 15) * 4, e4 = (tid >> 4) * 4;
  float acc[4][4];
#pragma unroll
  for (int i = 0; i < 4; ++i)
#pragma unroll
    for (int j = 0; j < 4; ++j) acc[i][j] = 0.f;

  for (int kc = 0; kc < 2; ++kc) {
    __syncthreads();
    for (int idx = tid; idx < 1024; idx += 256) {
      int k = idx >> 4, tq = idx & 15;
      *(float4*)&a_lds[k][tq * 4] =
          *(const float4*)&yds[(((size_t)(b * 128 + kc * 64 + k) * 64) + oy) * 64 + tq * 4];
    }
    for (int idx = tid; idx < 1024; idx += 256) {
      int j = idx >> 4, kq = idx & 15;
      float4 v = *(const float4*)&in_w[(size_t)(et * 64 + j) * 128 + kc * 64 + kq * 4];
      w_lds[kq * 4 + 0][j] = v.x; w_lds[kq * 4 + 1][j] = v.y;
      w_lds[kq * 4 + 2][j] = v.z; w_lds[kq * 4 + 3][j] = v.w;
    }
    __syncthreads();
#pragma unroll 8
    for (int k = 0; k < 64; ++k) {
      float4 a4 = *(const float4*)&a_lds[k][t4];
      float4 b4 = *(const float4*)&w_lds[k][e4];
      float av[4] = {a4.x, a4.y, a4.z, a4.w};
      float bv[4] = {b4.x, b4.y, b4.z, b4.w};
#pragma unroll
      for (int i = 0; i < 4; ++i)
#pragma unroll
        for (int j = 0; j < 4; ++j) acc[i][j] = fmaf(av[i], bv[j], acc[i][j]);
    }
  }
  const int e0 = et * 64 + e4;
#pragma unroll
  for (int i = 0; i < 4; ++i) {
    int t = oy * 64 + t4 + i;
    float4 v = make_float4(acc[i][0], acc[i][1], acc[i][2], acc[i][3]);
    float* dst = (e0 < 256) ? (xpre + ((size_t)(b * 4096 + t)) * 256 + e0)
                            : (z + ((size_t)(b * 4096 + t)) * 256 + (e0 - 256));
    *(float4*)dst = v;
  }
}

// =============== K3: depthwise causal conv1d (k=4) + SiLU; f32 + bf16 out ===============
__global__ __launch_bounds__(256) void k3_conv1d_silu(
    const float* __restrict__ xpre, const float* __restrict__ w,
    const float* __restrict__ bvec, float* __restrict__ xin,
    unsigned short* __restrict__ xinbf) {
  int i = blockIdx.x * 256 + threadIdx.x;
  int e4 = (i & 63) * 4;
  int t = (i >> 6) & 4095;
  int b = i >> 18;
  const float* base = xpre + (size_t)b * 4096 * 256;
  float4 zero = make_float4(0.f, 0.f, 0.f, 0.f);
  float4 r0 = (t >= 3) ? *(const float4*)&base[(size_t)(t - 3) * 256 + e4] : zero;
  float4 r1 = (t >= 2) ? *(const float4*)&base[(size_t)(t - 2) * 256 + e4] : zero;
  float4 r2 = (t >= 1) ? *(const float4*)&base[(size_t)(t - 1) * 256 + e4] : zero;
  float4 r3 = *(const float4*)&base[(size_t)t * 256 + e4];
  float4 w0 = *(const float4*)&w[(e4 + 0) * 4];
  float4 w1 = *(const float4*)&w[(e4 + 1) * 4];
  float4 w2 = *(const float4*)&w[(e4 + 2) * 4];
  float4 w3 = *(const float4*)&w[(e4 + 3) * 4];
  float4 bv = *(const float4*)&bvec[e4];
  float o0 = bv.x + w0.x * r0.x + w0.y * r1.x + w0.z * r2.x + w0.w * r3.x;
  float o1 = bv.y + w1.x * r0.y + w1.y * r1.y + w1.z * r2.y + w1.w * r3.y;
  float o2 = bv.z + w2.x * r0.z + w2.y * r1.z + w2.z * r2.z + w2.w * r3.z;
  float o3 = bv.w + w3.x * r0.w + w3.y * r1.w + w3.z * r2.w + w3.w * r3.w;
  float s0 = fast_silu(o0), s1 = fast_silu(o1), s2 = fast_silu(o2), s3 = fast_silu(o3);
  size_t off = ((size_t)b * 4096 + t) * 256 + e4;
  *(float4*)&xin[off] = make_float4(s0, s1, s2, s3);
  unsigned long long p = (unsigned long long)f2bf(s0)
                       | ((unsigned long long)f2bf(s1) << 16)
                       | ((unsigned long long)f2bf(s2) << 32)
                       | ((unsigned long long)f2bf(s3) << 48);
  *(unsigned long long*)&xinbf[off] = p;
}

// =============== K4: composed x_proj/dt_proj via bf16 MFMA -> delta (in-place), bc, dsum ===============
// Block = 16 tokens (1 M-tile = 1 scan chunk), grid 1024 (4/CU). 4 waves x 5 N-tiles
// (N padded to 320; tiles >=18 are zero-filled, discarded). Delta overwrites the
// block's own xin_bf rows after the barrier.
__global__ __launch_bounds__(256) void k4_mfma(
    const unsigned short* __restrict__ wcomp, const float* __restrict__ dtb,
    unsigned short* xinbf_delta /* in: xin_bf, out: delta (aliased) */,
    float* __restrict__ bc, float* __restrict__ dsum) {
  __shared__ unsigned short ld_delta[16][264];
  __shared__ float ld_bc[16][33];
  const int tid = threadIdx.x;
  const int lane = tid & 63;
  const int w = tid >> 6;
  const int col = lane & 15, quad = lane >> 4;
  const int tt = blockIdx.x & 255, b = blockIdx.x >> 8;
  const int t0 = tt * 16;

  // A preload (all waves share the same 16 token rows)
  bh8 afrag[8];
  {
    const unsigned short* arow =
        xinbf_delta + (size_t)(b * 4096 + t0 + col) * 256 + quad * 8;
#pragma unroll
    for (int kb = 0; kb < 8; ++kb) afrag[kb] = *(const bh8*)&arow[kb * 32];
  }
  f4v acc[5];
#pragma unroll
  for (int j = 0; j < 5; ++j) acc[j] = (f4v){0.f, 0.f, 0.f, 0.f};

  const int nt0 = w * 5;
  const unsigned short* wb = wcomp + (size_t)(nt0 * 16 + col) * 256 + quad * 8;
#pragma unroll
  for (int kb = 0; kb < 8; ++kb) {
#pragma unroll
    for (int j = 0; j < 5; ++j) {
      bh8 bfrag = *(const bh8*)&wb[(size_t)j * 4096 + kb * 32];
      acc[j] = __builtin_amdgcn_mfma_f32_16x16x32_bf16(afrag[kb], bfrag, acc[j], 0, 0, 0);
    }
  }
  // D layout: token = quad*4+r (M), n = (nt0+j)*16+col (N)
#pragma unroll
  for (int j = 0; j < 5; ++j) {
    const int n = (nt0 + j) * 16 + col;
    if (n < 256) {
      float bias = dtb[n];
#pragma unroll
      for (int r = 0; r < 4; ++r) {
        float s = acc[j][r] + bias;
        float dl = fmaxf(s, 0.f) + __logf(1.f + __expf(-fabsf(s)));  // softplus
        ld_delta[quad * 4 + r][n] = f2bf(dl);
      }
    } else if (n < 288) {
#pragma unroll
      for (int r = 0; r < 4; ++r) ld_bc[quad * 4 + r][n - 256] = acc[j][r];
    }
  }
  __syncthreads();   // LDS complete + all waves' A reads done before in-place stores

  // dsum for this chunk (thread = d; column sums, 2-way LDS aliasing = free)
  {
    float ds = 0.f;
#pragma unroll
    for (int i = 0; i < 16; ++i) ds += bf2f(ld_delta[i][tid]);
    dsum[((size_t)b * 256 + tt) * 256 + tid] = ds;
  }
  // delta out (overwrites xin_bf rows of this block)
#pragma unroll
  for (int it = 0; it < 4; ++it) {
    int idx = it * 256 + tid;
    int row = idx >> 6, d4 = (idx & 63) * 4;
    unsigned long long pk = *(const unsigned long long*)&ld_delta[row][d4];
    *(unsigned long long*)&xinbf_delta[((size_t)(b * 4096 + t0 + row)) * 256 + d4] = pk;
  }
  // bc out: 16 rows x 32 cols = 128 float4
  if (tid < 128) {
    int row = tid >> 3, q = (tid & 7) * 4;
    float4 v = make_float4(ld_bc[row][q], ld_bc[row][q + 1],
                           ld_bc[row][q + 2], ld_bc[row][q + 3]);
    *(float4*)&bc[((size_t)(b * 4096 + t0 + row)) * 32 + q] = v;
  }
}

// =============== K5a: pass 1 -> S[b][c][n][d] chunk-local scan ===============
__global__ __launch_bounds__(256) void k5a_scan1(
    const float* __restrict__ xin, const float* __restrict__ bc,
    const unsigned short* __restrict__ delta, const float* __restrict__ a2tab,
    float* __restrict__ S) {
  __shared__ __align__(16) float bct[TCH * 32];
  const int tid = threadIdx.x;
  const int d = tid;
  const int c = blockIdx.x & (NCH - 1), b = blockIdx.x >> 8;
  const int t0 = c * TCH;
  {
    const float* src = bc + (size_t)(b * 4096 + t0) * 32;
    for (int i = tid; i < TCH * 32; i += 256) bct[i] = src[i];
  }
  float A2[16];
#pragma unroll
  for (int j = 0; j < 4; ++j) {
    float4 a = *(const float4*)&a2tab[d * 16 + j * 4];
    A2[4 * j + 0] = a.x; A2[4 * j + 1] = a.y; A2[4 * j + 2] = a.z; A2[4 * j + 3] = a.w;
  }
  float h[16];
#pragma unroll
  for (int n = 0; n < 16; ++n) h[n] = 0.f;
  const unsigned short* pd = delta + (size_t)(b * 4096 + t0) * 256 + d;
  const float* px = xin + (size_t)(b * 4096 + t0) * 256 + d;
  __syncthreads();
#pragma unroll 4
  for (int i = 0; i < TCH; ++i) {
    float dl = bf2f(pd[(size_t)i * 256]);
    float xv = px[(size_t)i * 256];
    float dlx = dl * xv;
    const float* r = &bct[i * 32];
    float4 B0 = *(const float4*)&r[0];
    float4 B1 = *(const float4*)&r[4];
    float4 B2 = *(const float4*)&r[8];
    float4 B3 = *(const float4*)&r[12];
    float Bv[16] = {B0.x, B0.y, B0.z, B0.w, B1.x, B1.y, B1.z, B1.w,
                    B2.x, B2.y, B2.z, B2.w, B3.x, B3.y, B3.z, B3.w};
#pragma unroll
    for (int n = 0; n < 16; ++n)
      h[n] = fmaf(exp2f(dl * A2[n]), h[n], dlx * Bv[n]);
  }
  const size_t sbase = ((size_t)(b * NCH + c) * 16) * 256 + d;
#pragma unroll
  for (int n = 0; n < 16; ++n) S[sbase + (size_t)n * 256] = h[n];
}

// =============== K5b1: within-group combine (in-place exclusive prefix) ===============
__global__ __launch_bounds__(256) void k5b1_group(
    float* __restrict__ S, const float* __restrict__ dsum,
    const float* __restrict__ a2tab, float* __restrict__ Gs,
    float* __restrict__ Gd) {
  const int d = threadIdx.x;
  const int n = blockIdx.x & 15, g = (blockIdx.x >> 4) & (NG - 1),
            b = blockIdx.x >> 8;
  const float A2 = a2tab[d * 16 + n];
  float h = 0.f, cum = 0.f;
#pragma unroll 4
  for (int c16 = 0; c16 < GSZ; ++c16) {
    int c = g * GSZ + c16;
    size_t si = ((size_t)(b * NCH + c) * 16 + n) * 256 + d;
    float s = S[si];
    float dsv = dsum[((size_t)b * NCH + c) * 256 + d];
    float P = exp2f(A2 * dsv);
    S[si] = h;
    h = fmaf(P, h, s);
    cum += dsv;
  }
  Gs[((size_t)(b * NG + g) * 16 + n) * 256 + d] = h;
  if (n == 0) Gd[((size_t)b * NG + g) * 256 + d] = cum;
}

// =============== K5b2: scan group totals -> ginit in-place over Gs ===============
__global__ __launch_bounds__(256) void k5b2_groupscan(
    float* __restrict__ Gs, const float* __restrict__ Gd,
    const float* __restrict__ a2tab) {
  const int d = threadIdx.x;
  const int n = blockIdx.x & 15, b = blockIdx.x >> 4;
  const float A2 = a2tab[d * 16 + n];
  float h = 0.f;
#pragma unroll
  for (int g = 0; g < NG; ++g) {
    size_t gi = ((size_t)(b * NG + g) * 16 + n) * 256 + d;
    float s = Gs[gi];
    float P = exp2f(A2 * Gd[((size_t)b * NG + g) * 256 + d]);
    Gs[gi] = h;
    h = fmaf(P, h, s);
  }
}

// =============== K5c: pass 2 -> y, fused (+x*Dp)*silu(z) ===============
__global__ __launch_bounds__(256) void k5c_scan2(
    const float* __restrict__ xin, const float* __restrict__ bc,
    const unsigned short* __restrict__ delta, const float* __restrict__ z,
    const float* __restrict__ a2tab, const float* __restrict__ Dp,
    const float* __restrict__ dsum, const float* __restrict__ Gs,
    float* sy) {
  __shared__ __align__(16) float bct[TCH * 32];
  const int tid = threadIdx.x;
  const int d = tid;
  const int c = blockIdx.x & (NCH - 1), b = blockIdx.x >> 8;
  const int t0 = c * TCH;
  {
    const float* src = bc + (size_t)(b * 4096 + t0) * 32;
    for (int i = tid; i < TCH * 32; i += 256) bct[i] = src[i];
  }
  float A2[16];
#pragma unroll
  for (int j = 0; j < 4; ++j) {
    float4 a = *(const float4*)&a2tab[d * 16 + j * 4];
    A2[4 * j + 0] = a.x; A2[4 * j + 1] = a.y; A2[4 * j + 2] = a.z; A2[4 * j + 3] = a.w;
  }
  const float Dpd = Dp[d];
  const int g = c >> 4, c16 = c & 15;
  float dpref = 0.f;
  {
    const float* pds = dsum + ((size_t)b * NCH + g * GSZ) * 256 + d;
    for (int cc = 0; cc < c16; ++cc) dpref += pds[(size_t)cc * 256];
  }
  const size_t sbase = ((size_t)(b * NCH + c) * 16) * 256 + d;
  const size_t gbase = ((size_t)(b * NG + g) * 16) * 256 + d;
  float h[16];
#pragma unroll
  for (int n = 0; n < 16; ++n) {
    float gi = Gs[gbase + (size_t)n * 256];
    float hl = sy[sbase + (size_t)n * 256];
    h[n] = fmaf(exp2f(A2[n] * dpref), gi, hl);
  }
  const size_t base = (size_t)(b * 4096 + t0) * 256 + d;
  const unsigned short* pd = delta + base;
  const float* px = xin + base;
  const float* pz = z + base;
  float* py = sy + base;
  __syncthreads();
#pragma unroll 4
  for (int i = 0; i < TCH; ++i) {
    float dl = bf2f(pd[(size_t)i * 256]);
    float xv = px[(size_t)i * 256];
    float zv = pz[(size_t)i * 256];
    float dlx = dl * xv;
    const float* r = &bct[i * 32];
    float4 B0 = *(const float4*)&r[0];
    float4 B1 = *(const float4*)&r[4];
    float4 B2 = *(const float4*)&r[8];
    float4 B3 = *(const float4*)&r[12];
    float4 C0 = *(const float4*)&r[16];
    float4 C1 = *(const float4*)&r[20];
    float4 C2 = *(const float4*)&r[24];
    float4 C3 = *(const float4*)&r[28];
    float Bv[16] = {B0.x, B0.y, B0.z, B0.w, B1.x, B1.y, B1.z, B1.w,
                    B2.x, B2.y, B2.z, B2.w, B3.x, B3.y, B3.z, B3.w};
    float Cv[16] = {C0.x, C0.y, C0.z, C0.w, C1.x, C1.y, C1.z, C1.w,
                    C2.x, C2.y, C2.z, C2.w, C3.x, C3.y, C3.z, C3.w};
    float y = 0.f;
#pragma unroll
    for (int n = 0; n < 16; ++n) {
      h[n] = fmaf(exp2f(dl * A2[n]), h[n], dlx * Bv[n]);
      y = fmaf(h[n], Cv[n], y);
    }
    py[(size_t)i * 256] = (y + xv * Dpd) * fast_silu(zv);
  }
}

// =============== K6: out_proj GEMM + residual ===============
__global__ __launch_bounds__(256) void k6_outproj(
    const float* __restrict__ yact, const float* __restrict__ out_w,
    const float* __restrict__ yds, float* __restrict__ out) {
  __shared__ __align__(16) float a_lds[64][68];
  __shared__ __align__(16) float w_lds[64][132];
  const int tid = threadIdx.x;
  const int oy = blockIdx.x & 63, b = blockIdx.x >> 6;
  const int t4 = (tid & 15) * 4, c8 = (tid >> 4) * 8;
  float acc[4][8];
#pragma unroll
  for (int i = 0; i < 4; ++i)
#pragma unroll
    for (int j = 0; j < 8; ++j) acc[i][j] = 0.f;

  for (int kc = 0; kc < 4; ++kc) {
    __syncthreads();
    for (int idx = tid; idx < 1024; idx += 256) {
      int tl = idx >> 4; int e4 = (idx & 15) * 4;
      float4 v = *(const float4*)&yact[((size_t)(b * 4096 + oy * 64 + tl)) * 256 + kc * 64 + e4];
      a_lds[e4 + 0][tl] = v.x; a_lds[e4 + 1][tl] = v.y;
      a_lds[e4 + 2][tl] = v.z; a_lds[e4 + 3][tl] = v.w;
    }
    for (int idx = tid; idx < 2048; idx += 256) {
      int cc = idx >> 4, kq = idx & 15;
      float4 v = *(const float4*)&out_w[(size_t)cc * 256 + kc * 64 + kq * 4];
      w_lds[kq * 4 + 0][cc] = v.x; w_lds[kq * 4 + 1][cc] = v.y;
      w_lds[kq * 4 + 2][cc] = v.z; w_lds[kq * 4 + 3][cc] = v.w;
    }
    __syncthreads();
#pragma unroll 4
    for (int k = 0; k < 64; ++k) {
      float4 a4 = *(const float4*)&a_lds[k][t4];
      float4 b0 = *(const float4*)&w_lds[k][c8];
      float4 b1 = *(const float4*)&w_lds[k][c8 + 4];
      float av[4] = {a4.x, a4.y, a4.z, a4.w};
      float bv[8] = {b0.x, b0.y, b0.z, b0.w, b1.x, b1.y, b1.z, b1.w};
#pragma unroll
      for (int i = 0; i < 4; ++i)
#pragma unroll
        for (int j = 0; j < 8; ++j) acc[i][j] = fmaf(av[i], bv[j], acc[i][j]);
    }
  }
#pragma unroll
  for (int j = 0; j < 8; ++j) {
    int cc = c8 + j;
    size_t base = (((size_t)(b * 128 + cc) * 64) + oy) * 64 + t4;
    float4 r = *(const float4*)&yds[base];
    *(float4*)&out[base] = make_float4(acc[0][j] + r.x, acc[1][j] + r.y,
                                       acc[2][j] + r.z, acc[3][j] + r.w);
  }
}

// =============== launch ===============
extern "C" void kernel_launch(void* const* d_in, const int* in_sizes, int n_in,
                              void* d_out, int out_size, void* d_ws, size_t ws_size,
                              hipStream_t stream) {
  (void)in_sizes; (void)n_in; (void)out_size; (void)ws_size;
  const float* x        = (const float*)d_in[0];
  const float* conv_w   = (const float*)d_in[1];
  const float* conv_b   = (const float*)d_in[2];
  const float* bn_g     = (const float*)d_in[3];
  const float* bn_b     = (const float*)d_in[4];
  const float* bn_mean  = (const float*)d_in[5];
  const float* bn_var   = (const float*)d_in[6];
  const float* in_w     = (const float*)d_in[7];
  const float* conv1d_w = (const float*)d_in[8];
  const float* conv1d_b = (const float*)d_in[9];
  const float* xproj_w  = (const float*)d_in[10];
  const float* dtproj_w = (const float*)d_in[11];
  const float* dtproj_b = (const float*)d_in[12];
  const float* A_log    = (const float*)d_in[13];
  const float* Dp       = (const float*)d_in[14];
  const float* out_w    = (const float*)d_in[15];
  float* ws = (float*)d_ws;
  float* out = (float*)d_out;

  k0_prep<<<625, 256, 0, stream>>>(conv_w, conv_b, bn_g, bn_b, bn_mean, bn_var,
                                   xproj_w, A_log, dtproj_w, ws);
  k0b_transpose<<<1024, 256, 0, stream>>>(x, (unsigned short*)(ws + OFF_XT));
  k1_conv_mfma<<<512, 256, 0, stream>>>((const unsigned short*)(ws + OFF_XT),
                                        (const unsigned short*)(ws + OFF_WBF),
                                        ws + OFF_BIAS2, ws + OFF_YDS);
  k2_inproj<<<2048, 256, 0, stream>>>(ws + OFF_YDS, in_w, ws + OFF_XPRE, ws + OFF_Z);
  k3_conv1d_silu<<<4096, 256, 0, stream>>>(ws + OFF_XPRE, conv1d_w, conv1d_b,
                                           ws + OFF_XIN,
                                           (unsigned short*)(ws + OFF_XT));
  k4_mfma<<<1024, 256, 0, stream>>>((const unsigned short*)(ws + OFF_WCMP),
                                    dtproj_b, (unsigned short*)(ws + OFF_XT),
                                    ws + OFF_BC, ws + OFF_DSUM);
  k5a_scan1<<<1024, 256, 0, stream>>>(ws + OFF_XIN, ws + OFF_BC,
                                      (const unsigned short*)(ws + OFF_XT),
                                      ws + OFF_A2, ws + OFF_XPRE);
  k5b1_group<<<1024, 256, 0, stream>>>(ws + OFF_XPRE, ws + OFF_DSUM, ws + OFF_A2,
                                       ws + OFF_GS, ws + OFF_GD);
  k5b2_groupscan<<<64, 256, 0, stream>>>(ws + OFF_GS, ws + OFF_GD, ws + OFF_A2);
  k5c_scan2<<<1024, 256, 0, stream>>>(ws + OFF_XIN, ws + OFF_BC,
                                      (const unsigned short*)(ws + OFF_XT),
                                      ws + OFF_Z, ws + OFF_A2, Dp, ws + OFF_DSUM,
                                      ws + OFF_GS, ws + OFF_XPRE);
  k6_outproj<<<256, 256, 0, stream>>>(ws + OFF_YACT, out_w, ws + OFF_YDS, out);
}

// Round 9
// 259.598 us; speedup vs baseline: 1.2377x; 1.1295x over previous
//
#include <hip/hip_runtime.h>
#include <math.h>

// ---------------- problem sizes ----------------
#define NB 4
#define LTOK 4096
#define DM 128
#define DI 256
#define NCH 256    // scan chunks
#define TCH 16     // steps per chunk
#define GSZ 16     // chunks per combine group
#define NG  16     // groups = NCH/GSZ

// ---------------- workspace layout (float offsets) ----------------
#define OFF_A2     0u          // A2 table [256d][16n] (4096)
#define OFF_BIAS2  73728u      // folded conv+bn bias [128]
#define OFF_YDS    84096u      // gelu output f32 [4][128][64][64] (2097152)
#define OFF_XPRE   2181248u    // [4][4096][256] f32; ALIASED: S[b][c][n][d] after k3
#define OFF_Z      6375552u    // [4][4096][256] f32
#define OFF_DELTA  10569856u   // bf16 delta [4][4096][256] (2097152 fl)
#define OFF_YABF   12667008u   // bf16 yact [4][4096][256] (2097152 fl)
#define OFF_BC     14764160u   // [4][4096][32]: 0-15 B, 16-31 C (524288)
#define OFF_DSUM   15288448u   // [4][256c][256d] (262144)
#define OFF_GS     15550592u   // [4][16g][16n][256d] (262144)
#define OFF_GD     15812736u   // [4][16g][256d] (16384)
#define OFF_XT     15829120u   // bf16: x-transpose (k0b/k1); then xin_bf [4][4096][256]
#define OFF_WBF    17926272u   // bf16 conv weights*bn_inv [128co][9tap][64ci] (36864)
#define OFF_WCMP   17963136u   // bf16 composed xproj weights [320n][256k] (40960)
#define OFF_YDSBF  18004096u   // bf16 u t-major [4][4096][128] (1048576)
#define OFF_INWBF  19052672u   // bf16 in_w [512e][128k] (32768)
#define OFF_OUTWBF 19085440u   // bf16 out_w [128cc][256e] (16384)
// total 19101824 floats = 76.4 MB (< proven 79.9 MB budget)

#define DEV __device__ __forceinline__
#define L2E 1.4426950408889634f

typedef short bh8 __attribute__((ext_vector_type(8)));   // 8 bf16 (4 VGPR)
typedef float f4v __attribute__((ext_vector_type(4)));

DEV float fast_silu(float v) {
  return v * __builtin_amdgcn_rcpf(1.f + __expf(-v));
}

DEV unsigned short f2bf(float f) {                       // round-to-nearest-even
  unsigned int u = __float_as_uint(f);
  u = (u + 0x7FFFu + ((u >> 16) & 1u)) >> 16;
  return (unsigned short)u;
}

DEV float bf2f(unsigned short us) {
  return __uint_as_float((unsigned int)us << 16);
}

// =============== K0: all weight prep ===============
__global__ __launch_bounds__(256) void k0_prep(
    const float* __restrict__ conv_w, const float* __restrict__ conv_b,
    const float* __restrict__ bn_g, const float* __restrict__ bn_b,
    const float* __restrict__ bn_mean, const float* __restrict__ bn_var,
    const float* __restrict__ xproj_w, const float* __restrict__ A_log,
    const float* __restrict__ dtw, const float* __restrict__ in_w,
    const float* __restrict__ out_w, float* __restrict__ ws) {
  int i = blockIdx.x * 256 + threadIdx.x;
  if (i < 73728) {
    int ci = i & 63; int tap = (i >> 6) % 9; int co = i / 576;
    float inv = bn_g[co] * rsqrtf(bn_var[co] + 1e-5f);
    ((unsigned short*)(ws + OFF_WBF))[i] = f2bf(conv_w[co * 576 + ci * 9 + tap] * inv);
  } else if (i < 73856) {
    int co = i - 73728;
    float inv = bn_g[co] * rsqrtf(bn_var[co] + 1e-5f);
    ws[OFF_BIAS2 + co] = (conv_b[co] - bn_mean[co]) * inv + bn_b[co];
  } else if (i < 77952) {
    int j = i - 73856;
    ws[OFF_A2 + j] = -__expf(A_log[j]) * L2E;
  } else if (i < 159872) {
    // wcomp[n][k], n in [0,320)
    int j = i - 77952;
    int n = j >> 8, k = j & 255;
    float v = 0.f;
    if (n < 256) {
#pragma unroll
      for (int r = 0; r < 8; ++r)
        v = fmaf(dtw[n * 8 + r], xproj_w[r * 256 + k], v);
    } else if (n < 288) {
      v = xproj_w[(8 + n - 256) * 256 + k];
    }
    ((unsigned short*)(ws + OFF_WCMP))[j] = f2bf(v);
  } else if (i < 225408) {
    int j = i - 159872;                                  // [512e][128k]
    ((unsigned short*)(ws + OFF_INWBF))[j] = f2bf(in_w[j]);
  } else if (i < 258176) {
    int j = i - 225408;                                  // [128cc][256e]
    ((unsigned short*)(ws + OFF_OUTWBF))[j] = f2bf(out_w[j]);
  }
}

// =============== K0b: transpose x -> xt[b][iy][ix][ci] bf16 ===============
__global__ __launch_bounds__(256) void k0b_transpose(
    const float* __restrict__ x, unsigned short* __restrict__ xt) {
  __shared__ float t[64][65];
  const int tid = threadIdx.x;
  const int ixh = blockIdx.x & 1;
  const int iy = (blockIdx.x >> 1) & 127;
  const int b = blockIdx.x >> 8;
  {
    const int ixl = tid & 63, cw = tid >> 6;
#pragma unroll 4
    for (int i = 0; i < 16; ++i) {
      int ci = cw * 16 + i;
      t[ci][ixl] = x[(((size_t)(b * 64 + ci) * 128) + iy) * 128 + ixh * 64 + ixl];
    }
  }
  __syncthreads();
  {
    const int cil = tid & 63, iw = tid >> 6;
    unsigned short* dst = xt + (((size_t)(b * 128 + iy) * 128) + ixh * 64) * 64;
#pragma unroll 4
    for (int i = 0; i < 16; ++i) {
      int ix = iw * 16 + i;
      dst[ix * 64 + cil] = f2bf(t[cil][ix]);
    }
  }
}

// =============== K1: conv3x3 s2 + BN + GELU via bf16 MFMA; emits yds f32 + ydsbf ===============
__global__ __launch_bounds__(256) void k1_conv_mfma(
    const unsigned short* __restrict__ xt, const unsigned short* __restrict__ wbf,
    const float* __restrict__ bias2, float* __restrict__ yds,
    unsigned short* __restrict__ ydsbf) {
  __shared__ unsigned short ldt[64][66];
  const int tid = threadIdx.x;
  const int lane = tid & 63;
  const int w = tid >> 6;
  const int col = lane & 15, quad = lane >> 4;
  const int cohalf = blockIdx.x & 1;
  const int oy = (blockIdx.x >> 1) & 63;
  const int b = blockIdx.x >> 7;
  const int co0 = cohalf * 64 + (w & 1) * 32;
  const int tok0 = (w >> 1) * 32;
  const int iy0 = 2 * oy - 1;
  const bh8 bzero = {};
  f4v acc[2][2];
#pragma unroll
  for (int mt = 0; mt < 2; ++mt)
#pragma unroll
    for (int nt = 0; nt < 2; ++nt) acc[mt][nt] = (f4v){0.f, 0.f, 0.f, 0.f};

  const unsigned short* ap0 = wbf + (size_t)(co0 + col) * 576;
  const unsigned short* ap1 = wbf + (size_t)(co0 + 16 + col) * 576;

  for (int tap = 0; tap < 9; ++tap) {
    const int kh = tap / 3, kw = tap - kh * 3;
    const int iy = iy0 + kh;
    const int ix0 = 2 * (tok0 + col) - 1 + kw;
    const int ix1 = ix0 + 32;
    const unsigned short* xrow = xt + (long)(b * 128 + iy) * 8192;
    const bool ok0 = (iy >= 0) && (ix0 >= 0);
    const bool ok1 = (iy >= 0);
#pragma unroll
    for (int kc = 0; kc < 2; ++kc) {
      const int cib = kc * 32 + quad * 8;
      bh8 a0 = *(const bh8*)&ap0[tap * 64 + cib];
      bh8 a1 = *(const bh8*)&ap1[tap * 64 + cib];
      bh8 b0 = *(const bh8*)&xrow[(long)ix0 * 64 + cib];
      bh8 b1 = *(const bh8*)&xrow[(long)ix1 * 64 + cib];
      if (!ok0) b0 = bzero;
      if (!ok1) b1 = bzero;
      acc[0][0] = __builtin_amdgcn_mfma_f32_16x16x32_bf16(a0, b0, acc[0][0], 0, 0, 0);
      acc[1][0] = __builtin_amdgcn_mfma_f32_16x16x32_bf16(a1, b0, acc[1][0], 0, 0, 0);
      acc[0][1] = __builtin_amdgcn_mfma_f32_16x16x32_bf16(a0, b1, acc[0][1], 0, 0, 0);
      acc[1][1] = __builtin_amdgcn_mfma_f32_16x16x32_bf16(a1, b1, acc[1][1], 0, 0, 0);
    }
  }
#pragma unroll
  for (int mt = 0; mt < 2; ++mt)
#pragma unroll
    for (int nt = 0; nt < 2; ++nt) {
      const int tok = tok0 + nt * 16 + col;
#pragma unroll
      for (int r = 0; r < 4; ++r) {
        const int co = co0 + mt * 16 + quad * 4 + r;
        float v = acc[mt][nt][r] + bias2[co];
        float g = 0.5f * v * (1.f + erff(v * 0.70710678118f));
        yds[(((size_t)(b * 128 + co) * 64) + oy) * 64 + tok] = g;
        ldt[tok][(w & 1) * 32 + mt * 16 + quad * 4 + r] = f2bf(g);
      }
    }
  __syncthreads();
  // bf16 t-major write: ydsbf[(b*4096 + oy*64 + tok)*128 + cohalf*64 + cg]
  {
    const int tok = tid >> 2, cg = (tid & 3) * 16;
    unsigned short* dst =
        ydsbf + ((size_t)(b * 4096 + oy * 64 + tok)) * 128 + cohalf * 64 + cg;
#pragma unroll
    for (int j = 0; j < 8; ++j)
      ((unsigned int*)dst)[j] = *(const unsigned int*)&ldt[tok][cg + 2 * j];
  }
}

// =============== K2: in_proj via bf16 MFMA -> xpre f32, z f32 (t-major) ===============
// Block = 16 tokens, grid 1024. 4 waves x 8 N-tiles (N=512), K=128.
__global__ __launch_bounds__(256) void k2_mfma(
    const unsigned short* __restrict__ ydsbf, const unsigned short* __restrict__ inwbf,
    float* __restrict__ xpre, float* __restrict__ z) {
  const int tid = threadIdx.x;
  const int lane = tid & 63;
  const int w = tid >> 6;
  const int col = lane & 15, quad = lane >> 4;
  const int tt = blockIdx.x & 255, b = blockIdx.x >> 8;
  const int t0 = tt * 16;
  bh8 afrag[4];
  {
    const unsigned short* arow = ydsbf + (size_t)(b * 4096 + t0 + col) * 128 + quad * 8;
#pragma unroll
    for (int kb = 0; kb < 4; ++kb) afrag[kb] = *(const bh8*)&arow[kb * 32];
  }
  f4v acc[8];
#pragma unroll
  for (int j = 0; j < 8; ++j) acc[j] = (f4v){0.f, 0.f, 0.f, 0.f};
  const int nt0 = w * 8;
  const unsigned short* wb = inwbf + (size_t)(nt0 * 16 + col) * 128 + quad * 8;
#pragma unroll
  for (int kb = 0; kb < 4; ++kb) {
#pragma unroll
    for (int j = 0; j < 8; ++j) {
      bh8 bfrag = *(const bh8*)&wb[(size_t)j * 2048 + kb * 32];
      acc[j] = __builtin_amdgcn_mfma_f32_16x16x32_bf16(afrag[kb], bfrag, acc[j], 0, 0, 0);
    }
  }
#pragma unroll
  for (int j = 0; j < 8; ++j) {
    const int e = (nt0 + j) * 16 + col;
#pragma unroll
    for (int r = 0; r < 4; ++r) {
      const int t = t0 + quad * 4 + r;
      if (e < 256) xpre[((size_t)(b * 4096 + t)) * 256 + e] = acc[j][r];
      else z[((size_t)(b * 4096 + t)) * 256 + e - 256] = acc[j][r];
    }
  }
}

// =============== K3: depthwise causal conv1d (k=4) + SiLU -> xinbf only ===============
__global__ __launch_bounds__(256) void k3_conv1d_silu(
    const float* __restrict__ xpre, const float* __restrict__ w,
    const float* __restrict__ bvec, unsigned short* __restrict__ xinbf) {
  int i = blockIdx.x * 256 + threadIdx.x;
  int e4 = (i & 63) * 4;
  int t = (i >> 6) & 4095;
  int b = i >> 18;
  const float* base = xpre + (size_t)b * 4096 * 256;
  float4 zero = make_float4(0.f, 0.f, 0.f, 0.f);
  float4 r0 = (t >= 3) ? *(const float4*)&base[(size_t)(t - 3) * 256 + e4] : zero;
  float4 r1 = (t >= 2) ? *(const float4*)&base[(size_t)(t - 2) * 256 + e4] : zero;
  float4 r2 = (t >= 1) ? *(const float4*)&base[(size_t)(t - 1) * 256 + e4] : zero;
  float4 r3 = *(const float4*)&base[(size_t)t * 256 + e4];
  float4 w0 = *(const float4*)&w[(e4 + 0) * 4];
  float4 w1 = *(const float4*)&w[(e4 + 1) * 4];
  float4 w2 = *(const float4*)&w[(e4 + 2) * 4];
  float4 w3 = *(const float4*)&w[(e4 + 3) * 4];
  float4 bv = *(const float4*)&bvec[e4];
  float o0 = bv.x + w0.x * r0.x + w0.y * r1.x + w0.z * r2.x + w0.w * r3.x;
  float o1 = bv.y + w1.x * r0.y + w1.y * r1.y + w1.z * r2.y + w1.w * r3.y;
  float o2 = bv.z + w2.x * r0.z + w2.y * r1.z + w2.z * r2.z + w2.w * r3.z;
  float o3 = bv.w + w3.x * r0.w + w3.y * r1.w + w3.z * r2.w + w3.w * r3.w;
  float s0 = fast_silu(o0), s1 = fast_silu(o1), s2 = fast_silu(o2), s3 = fast_silu(o3);
  size_t off = ((size_t)b * 4096 + t) * 256 + e4;
  unsigned long long p = (unsigned long long)f2bf(s0)
                       | ((unsigned long long)f2bf(s1) << 16)
                       | ((unsigned long long)f2bf(s2) << 32)
                       | ((unsigned long long)f2bf(s3) << 48);
  *(unsigned long long*)&xinbf[off] = p;
}

// =============== K4: composed x_proj/dt_proj via bf16 MFMA -> delta, bc, dsum ===============
__global__ __launch_bounds__(256) void k4_mfma(
    const unsigned short* __restrict__ wcomp, const float* __restrict__ dtb,
    const unsigned short* __restrict__ xinbf, unsigned short* __restrict__ delta,
    float* __restrict__ bc, float* __restrict__ dsum) {
  __shared__ unsigned short ld_delta[16][264];
  __shared__ float ld_bc[16][33];
  const int tid = threadIdx.x;
  const int lane = tid & 63;
  const int w = tid >> 6;
  const int col = lane & 15, quad = lane >> 4;
  const int tt = blockIdx.x & 255, b = blockIdx.x >> 8;
  const int t0 = tt * 16;

  bh8 afrag[8];
  {
    const unsigned short* arow = xinbf + (size_t)(b * 4096 + t0 + col) * 256 + quad * 8;
#pragma unroll
    for (int kb = 0; kb < 8; ++kb) afrag[kb] = *(const bh8*)&arow[kb * 32];
  }
  f4v acc[5];
#pragma unroll
  for (int j = 0; j < 5; ++j) acc[j] = (f4v){0.f, 0.f, 0.f, 0.f};

  const int nt0 = w * 5;
  const unsigned short* wb = wcomp + (size_t)(nt0 * 16 + col) * 256 + quad * 8;
#pragma unroll
  for (int kb = 0; kb < 8; ++kb) {
#pragma unroll
    for (int j = 0; j < 5; ++j) {
      bh8 bfrag = *(const bh8*)&wb[(size_t)j * 4096 + kb * 32];
      acc[j] = __builtin_amdgcn_mfma_f32_16x16x32_bf16(afrag[kb], bfrag, acc[j], 0, 0, 0);
    }
  }
#pragma unroll
  for (int j = 0; j < 5; ++j) {
    const int n = (nt0 + j) * 16 + col;
    if (n < 256) {
      float bias = dtb[n];
#pragma unroll
      for (int r = 0; r < 4; ++r) {
        float s = acc[j][r] + bias;
        float dl = fmaxf(s, 0.f) + __logf(1.f + __expf(-fabsf(s)));  // softplus
        ld_delta[quad * 4 + r][n] = f2bf(dl);
      }
    } else if (n < 288) {
#pragma unroll
      for (int r = 0; r < 4; ++r) ld_bc[quad * 4 + r][n - 256] = acc[j][r];
    }
  }
  __syncthreads();

  // dsum for this chunk (thread = d)
  {
    float ds = 0.f;
#pragma unroll
    for (int i = 0; i < 16; ++i) ds += bf2f(ld_delta[i][tid]);
    dsum[((size_t)b * 256 + tt) * 256 + tid] = ds;
  }
  // delta out
#pragma unroll
  for (int it = 0; it < 4; ++it) {
    int idx = it * 256 + tid;
    int row = idx >> 6, d4 = (idx & 63) * 4;
    unsigned long long pk = *(const unsigned long long*)&ld_delta[row][d4];
    *(unsigned long long*)&delta[((size_t)(b * 4096 + t0 + row)) * 256 + d4] = pk;
  }
  // bc out
  if (tid < 128) {
    int row = tid >> 3, q = (tid & 7) * 4;
    float4 v = make_float4(ld_bc[row][q], ld_bc[row][q + 1],
                           ld_bc[row][q + 2], ld_bc[row][q + 3]);
    *(float4*)&bc[((size_t)(b * 4096 + t0 + row)) * 32 + q] = v;
  }
}

// =============== K5a: pass 1 -> S[b][c][n][d] chunk-local scan ===============
__global__ __launch_bounds__(256) void k5a_scan1(
    const unsigned short* __restrict__ xinbf, const float* __restrict__ bc,
    const unsigned short* __restrict__ delta, const float* __restrict__ a2tab,
    float* __restrict__ S) {
  __shared__ __align__(16) float bct[TCH * 32];
  const int tid = threadIdx.x;
  const int d = tid;
  const int c = blockIdx.x & (NCH - 1), b = blockIdx.x >> 8;
  const int t0 = c * TCH;
  {
    const float* src = bc + (size_t)(b * 4096 + t0) * 32;
    for (int i = tid; i < TCH * 32; i += 256) bct[i] = src[i];
  }
  float A2[16];
#pragma unroll
  for (int j = 0; j < 4; ++j) {
    float4 a = *(const float4*)&a2tab[d * 16 + j * 4];
    A2[4 * j + 0] = a.x; A2[4 * j + 1] = a.y; A2[4 * j + 2] = a.z; A2[4 * j + 3] = a.w;
  }
  float h[16];
#pragma unroll
  for (int n = 0; n < 16; ++n) h[n] = 0.f;
  const unsigned short* pd = delta + (size_t)(b * 4096 + t0) * 256 + d;
  const unsigned short* px = xinbf + (size_t)(b * 4096 + t0) * 256 + d;
  __syncthreads();
#pragma unroll 4
  for (int i = 0; i < TCH; ++i) {
    float dl = bf2f(pd[(size_t)i * 256]);
    float xv = bf2f(px[(size_t)i * 256]);
    float dlx = dl * xv;
    const float* r = &bct[i * 32];
    float4 B0 = *(const float4*)&r[0];
    float4 B1 = *(const float4*)&r[4];
    float4 B2 = *(const float4*)&r[8];
    float4 B3 = *(const float4*)&r[12];
    float Bv[16] = {B0.x, B0.y, B0.z, B0.w, B1.x, B1.y, B1.z, B1.w,
                    B2.x, B2.y, B2.z, B2.w, B3.x, B3.y, B3.z, B3.w};
#pragma unroll
    for (int n = 0; n < 16; ++n)
      h[n] = fmaf(exp2f(dl * A2[n]), h[n], dlx * Bv[n]);
  }
  const size_t sbase = ((size_t)(b * NCH + c) * 16) * 256 + d;
#pragma unroll
  for (int n = 0; n < 16; ++n) S[sbase + (size_t)n * 256] = h[n];
}

// =============== K5b1: within-group combine (in-place exclusive prefix) ===============
__global__ __launch_bounds__(256) void k5b1_group(
    float* __restrict__ S, const float* __restrict__ dsum,
    const float* __restrict__ a2tab, float* __restrict__ Gs,
    float* __restrict__ Gd) {
  const int d = threadIdx.x;
  const int n = blockIdx.x & 15, g = (blockIdx.x >> 4) & (NG - 1),
            b = blockIdx.x >> 8;
  const float A2 = a2tab[d * 16 + n];
  float h = 0.f, cum = 0.f;
#pragma unroll 4
  for (int c16 = 0; c16 < GSZ; ++c16) {
    int c = g * GSZ + c16;
    size_t si = ((size_t)(b * NCH + c) * 16 + n) * 256 + d;
    float s = S[si];
    float dsv = dsum[((size_t)b * NCH + c) * 256 + d];
    float P = exp2f(A2 * dsv);
    S[si] = h;
    h = fmaf(P, h, s);
    cum += dsv;
  }
  Gs[((size_t)(b * NG + g) * 16 + n) * 256 + d] = h;
  if (n == 0) Gd[((size_t)b * NG + g) * 256 + d] = cum;
}

// =============== K5b2: scan group totals -> ginit in-place over Gs ===============
__global__ __launch_bounds__(256) void k5b2_groupscan(
    float* __restrict__ Gs, const float* __restrict__ Gd,
    const float* __restrict__ a2tab) {
  const int d = threadIdx.x;
  const int n = blockIdx.x & 15, b = blockIdx.x >> 4;
  const float A2 = a2tab[d * 16 + n];
  float h = 0.f;
#pragma unroll
  for (int g = 0; g < NG; ++g) {
    size_t gi = ((size_t)(b * NG + g) * 16 + n) * 256 + d;
    float s = Gs[gi];
    float P = exp2f(A2 * Gd[((size_t)b * NG + g) * 256 + d]);
    Gs[gi] = h;
    h = fmaf(P, h, s);
  }
}

// =============== K5c: pass 2 -> yact bf16, fused (+x*Dp)*silu(z) ===============
__global__ __launch_bounds__(256) void k5c_scan2(
    const unsigned short* __restrict__ xinbf, const float* __restrict__ bc,
    const unsigned short* __restrict__ delta, const float* __restrict__ z,
    const float* __restrict__ a2tab, const float* __restrict__ Dp,
    const float* __restrict__ dsum, const float* __restrict__ Gs,
    const float* __restrict__ S, unsigned short* __restrict__ yabf) {
  __shared__ __align__(16) float bct[TCH * 32];
  const int tid = threadIdx.x;
  const int d = tid;
  const int c = blockIdx.x & (NCH - 1), b = blockIdx.x >> 8;
  const int t0 = c * TCH;
  {
    const float* src = bc + (size_t)(b * 4096 + t0) * 32;
    for (int i = tid; i < TCH * 32; i += 256) bct[i] = src[i];
  }
  float A2[16];
#pragma unroll
  for (int j = 0; j < 4; ++j) {
    float4 a = *(const float4*)&a2tab[d * 16 + j * 4];
    A2[4 * j + 0] = a.x; A2[4 * j + 1] = a.y; A2[4 * j + 2] = a.z; A2[4 * j + 3] = a.w;
  }
  const float Dpd = Dp[d];
  const int g = c >> 4, c16 = c & 15;
  float dpref = 0.f;
  {
    const float* pds = dsum + ((size_t)b * NCH + g * GSZ) * 256 + d;
    for (int cc = 0; cc < c16; ++cc) dpref += pds[(size_t)cc * 256];
  }
  const size_t sbase = ((size_t)(b * NCH + c) * 16) * 256 + d;
  const size_t gbase = ((size_t)(b * NG + g) * 16) * 256 + d;
  float h[16];
#pragma unroll
  for (int n = 0; n < 16; ++n) {
    float gi = Gs[gbase + (size_t)n * 256];
    float hl = S[sbase + (size_t)n * 256];
    h[n] = fmaf(exp2f(A2[n] * dpref), gi, hl);
  }
  const size_t base = (size_t)(b * 4096 + t0) * 256 + d;
  const unsigned short* pd = delta + base;
  const unsigned short* px = xinbf + base;
  const float* pz = z + base;
  unsigned short* py = yabf + base;
  __syncthreads();
#pragma unroll 4
  for (int i = 0; i < TCH; ++i) {
    float dl = bf2f(pd[(size_t)i * 256]);
    float xv = bf2f(px[(size_t)i * 256]);
    float zv = pz[(size_t)i * 256];
    float dlx = dl * xv;
    const float* r = &bct[i * 32];
    float4 B0 = *(const float4*)&r[0];
    float4 B1 = *(const float4*)&r[4];
    float4 B2 = *(const float4*)&r[8];
    float4 B3 = *(const float4*)&r[12];
    float4 C0 = *(const float4*)&r[16];
    float4 C1 = *(const float4*)&r[20];
    float4 C2 = *(const float4*)&r[24];
    float4 C3 = *(const float4*)&r[28];
    float Bv[16] = {B0.x, B0.y, B0.z, B0.w, B1.x, B1.y, B1.z, B1.w,
                    B2.x, B2.y, B2.z, B2.w, B3.x, B3.y, B3.z, B3.w};
    float Cv[16] = {C0.x, C0.y, C0.z, C0.w, C1.x, C1.y, C1.z, C1.w,
                    C2.x, C2.y, C2.z, C2.w, C3.x, C3.y, C3.z, C3.w};
    float y = 0.f;
#pragma unroll
    for (int n = 0; n < 16; ++n) {
      h[n] = fmaf(exp2f(dl * A2[n]), h[n], dlx * Bv[n]);
      y = fmaf(h[n], Cv[n], y);
    }
    py[(size_t)i * 256] = f2bf((y + xv * Dpd) * fast_silu(zv));
  }
}

// =============== K6: out_proj via bf16 MFMA + residual -> NCHW out ===============
// Block = 16 tokens (one ox run of 16 within an oy row), grid 1024. 4 waves x 2 N-tiles.
__global__ __launch_bounds__(256) void k6_mfma(
    const unsigned short* __restrict__ yabf, const unsigned short* __restrict__ outwbf,
    const float* __restrict__ yds, float* __restrict__ out) {
  __shared__ float ld[16][132];
  const int tid = threadIdx.x;
  const int lane = tid & 63;
  const int w = tid >> 6;
  const int col = lane & 15, quad = lane >> 4;
  const int tt = blockIdx.x & 255, b = blockIdx.x >> 8;
  const int t0 = tt * 16;
  const int oy = t0 >> 6, ox0 = t0 & 63;
  bh8 afrag[8];
  {
    const unsigned short* arow = yabf + (size_t)(b * 4096 + t0 + col) * 256 + quad * 8;
#pragma unroll
    for (int kb = 0; kb < 8; ++kb) afrag[kb] = *(const bh8*)&arow[kb * 32];
  }
  f4v acc[2];
#pragma unroll
  for (int j = 0; j < 2; ++j) acc[j] = (f4v){0.f, 0.f, 0.f, 0.f};
  const int nt0 = w * 2;
  const unsigned short* wb = outwbf + (size_t)(nt0 * 16 + col) * 256 + quad * 8;
#pragma unroll
  for (int kb = 0; kb < 8; ++kb) {
#pragma unroll
    for (int j = 0; j < 2; ++j) {
      bh8 bfrag = *(const bh8*)&wb[(size_t)j * 4096 + kb * 32];
      acc[j] = __builtin_amdgcn_mfma_f32_16x16x32_bf16(afrag[kb], bfrag, acc[j], 0, 0, 0);
    }
  }
#pragma unroll
  for (int j = 0; j < 2; ++j)
#pragma unroll
    for (int r = 0; r < 4; ++r)
      ld[quad * 4 + r][(nt0 + j) * 16 + col] = acc[j][r];
  __syncthreads();
  {
    const int cc = tid >> 1, half = tid & 1;
    size_t base = (((size_t)(b * 128 + cc) * 64) + oy) * 64 + ox0 + half * 8;
    float4 r0 = *(const float4*)&yds[base];
    float4 r1 = *(const float4*)&yds[base + 4];
    const int m0 = half * 8;
    float4 o0 = make_float4(ld[m0 + 0][cc] + r0.x, ld[m0 + 1][cc] + r0.y,
                            ld[m0 + 2][cc] + r0.z, ld[m0 + 3][cc] + r0.w);
    float4 o1 = make_float4(ld[m0 + 4][cc] + r1.x, ld[m0 + 5][cc] + r1.y,
                            ld[m0 + 6][cc] + r1.z, ld[m0 + 7][cc] + r1.w);
    *(float4*)&out[base] = o0;
    *(float4*)&out[base + 4] = o1;
  }
}

// =============== launch ===============
extern "C" void kernel_launch(void* const* d_in, const int* in_sizes, int n_in,
                              void* d_out, int out_size, void* d_ws, size_t ws_size,
                              hipStream_t stream) {
  (void)in_sizes; (void)n_in; (void)out_size; (void)ws_size;
  const float* x        = (const float*)d_in[0];
  const float* conv_w   = (const float*)d_in[1];
  const float* conv_b   = (const float*)d_in[2];
  const float* bn_g     = (const float*)d_in[3];
  const float* bn_b     = (const float*)d_in[4];
  const float* bn_mean  = (const float*)d_in[5];
  const float* bn_var   = (const float*)d_in[6];
  const float* in_w     = (const float*)d_in[7];
  const float* conv1d_w = (const float*)d_in[8];
  const float* conv1d_b = (const float*)d_in[9];
  const float* xproj_w  = (const float*)d_in[10];
  const float* dtproj_w = (const float*)d_in[11];
  const float* dtproj_b = (const float*)d_in[12];
  const float* A_log    = (const float*)d_in[13];
  const float* Dp       = (const float*)d_in[14];
  const float* out_w    = (const float*)d_in[15];
  float* ws = (float*)d_ws;
  float* out = (float*)d_out;

  k0_prep<<<1009, 256, 0, stream>>>(conv_w, conv_b, bn_g, bn_b, bn_mean, bn_var,
                                    xproj_w, A_log, dtproj_w, in_w, out_w, ws);
  k0b_transpose<<<1024, 256, 0, stream>>>(x, (unsigned short*)(ws + OFF_XT));
  k1_conv_mfma<<<512, 256, 0, stream>>>((const unsigned short*)(ws + OFF_XT),
                                        (const unsigned short*)(ws + OFF_WBF),
                                        ws + OFF_BIAS2, ws + OFF_YDS,
                                        (unsigned short*)(ws + OFF_YDSBF));
  k2_mfma<<<1024, 256, 0, stream>>>((const unsigned short*)(ws + OFF_YDSBF),
                                    (const unsigned short*)(ws + OFF_INWBF),
                                    ws + OFF_XPRE, ws + OFF_Z);
  k3_conv1d_silu<<<4096, 256, 0, stream>>>(ws + OFF_XPRE, conv1d_w, conv1d_b,
                                           (unsigned short*)(ws + OFF_XT));
  k4_mfma<<<1024, 256, 0, stream>>>((const unsigned short*)(ws + OFF_WCMP),
                                    dtproj_b, (const unsigned short*)(ws + OFF_XT),
                                    (unsigned short*)(ws + OFF_DELTA),
                                    ws + OFF_BC, ws + OFF_DSUM);
  k5a_scan1<<<1024, 256, 0, stream>>>((const unsigned short*)(ws + OFF_XT),
                                      ws + OFF_BC,
                                      (const unsigned short*)(ws + OFF_DELTA),
                                      ws + OFF_A2, ws + OFF_XPRE);
  k5b1_group<<<1024, 256, 0, stream>>>(ws + OFF_XPRE, ws + OFF_DSUM, ws + OFF_A2,
                                       ws + OFF_GS, ws + OFF_GD);
  k5b2_groupscan<<<64, 256, 0, stream>>>(ws + OFF_GS, ws + OFF_GD, ws + OFF_A2);
  k5c_scan2<<<1024, 256, 0, stream>>>((const unsigned short*)(ws + OFF_XT),
                                      ws + OFF_BC,
                                      (const unsigned short*)(ws + OFF_DELTA),
                                      ws + OFF_Z, ws + OFF_A2, Dp, ws + OFF_DSUM,
                                      ws + OFF_GS, ws + OFF_XPRE,
                                      (unsigned short*)(ws + OFF_YABF));
  k6_mfma<<<1024, 256, 0, stream>>>((const unsigned short*)(ws + OFF_YABF),
                                    (const unsigned short*)(ws + OFF_OUTWBF),
                                    ws + OFF_YDS, out);
}

// Round 10
// 240.947 us; speedup vs baseline: 1.3335x; 1.0774x over previous
//
#include <hip/hip_runtime.h>
#include <math.h>

// ---------------- problem sizes ----------------
#define NB 4
#define LTOK 4096
#define DM 128
#define DI 256
#define NCH 256    // scan chunks
#define TCH 16     // steps per chunk
#define GSZ 16     // chunks per combine group
#define NG  16     // groups = NCH/GSZ

// ---------------- workspace layout (float offsets) ----------------
#define OFF_A2     0u          // A2 table [256d][16n] (4096)
#define OFF_BIAS2  73728u      // folded conv+bn bias [128]
#define OFF_YDSR   84096u      // bf16 gelu NCHW [4][128][64][64] (1048576 fl)
#define OFF_XPRE   2181248u    // bf16 xpre [4][4096][256] (first 2097152 fl);
                               // then S f32 [4][256c][16n][256d] (4194304 fl, aliased)
#define OFF_Z      6375552u    // bf16 z [4][4096][256] (2097152 fl)
#define OFF_DELTA  10569856u   // bf16 delta [4][4096][256] (2097152 fl)
#define OFF_YABF   12667008u   // bf16 yact [4][4096][256] (2097152 fl)
#define OFF_BC     14764160u   // f32 [4][4096][32]: 0-15 B, 16-31 C (524288)
#define OFF_DSUM   15288448u   // [4][256c][256d] (262144)
#define OFF_GS     15550592u   // [4][16g][16n][256d] (262144)
#define OFF_GD     15812736u   // [4][16g][256d] (16384)
#define OFF_XT     15829120u   // bf16: x-transpose (k0b/k1); then xinbf [4][4096][256]
#define OFF_WBF    17926272u   // bf16 conv weights*bn_inv [128co][9tap][64ci] (36864)
#define OFF_WCMP   17963136u   // bf16 composed xproj weights [320n][256k] (40960)
#define OFF_YDSBF  18004096u   // bf16 u t-major [4][4096][128] (1048576)
#define OFF_INWBF  19052672u   // bf16 in_w [512e][128k] (32768)
#define OFF_OUTWBF 19085440u   // bf16 out_w [128cc][256e] (16384)
// total 19101824 floats = 76.4 MB

#define DEV __device__ __forceinline__
#define L2E 1.4426950408889634f

typedef short bh8 __attribute__((ext_vector_type(8)));   // 8 bf16 (4 VGPR)
typedef float f4v __attribute__((ext_vector_type(4)));

DEV float fast_silu(float v) {
  return v * __builtin_amdgcn_rcpf(1.f + __expf(-v));
}

DEV unsigned short f2bf(float f) {                       // round-to-nearest-even
  unsigned int u = __float_as_uint(f);
  u = (u + 0x7FFFu + ((u >> 16) & 1u)) >> 16;
  return (unsigned short)u;
}

DEV float bf2f(unsigned short us) {
  return __uint_as_float((unsigned int)us << 16);
}

// =============== K0: all weight prep ===============
__global__ __launch_bounds__(256) void k0_prep(
    const float* __restrict__ conv_w, const float* __restrict__ conv_b,
    const float* __restrict__ bn_g, const float* __restrict__ bn_b,
    const float* __restrict__ bn_mean, const float* __restrict__ bn_var,
    const float* __restrict__ xproj_w, const float* __restrict__ A_log,
    const float* __restrict__ dtw, const float* __restrict__ in_w,
    const float* __restrict__ out_w, float* __restrict__ ws) {
  int i = blockIdx.x * 256 + threadIdx.x;
  if (i < 73728) {
    int ci = i & 63; int tap = (i >> 6) % 9; int co = i / 576;
    float inv = bn_g[co] * rsqrtf(bn_var[co] + 1e-5f);
    ((unsigned short*)(ws + OFF_WBF))[i] = f2bf(conv_w[co * 576 + ci * 9 + tap] * inv);
  } else if (i < 73856) {
    int co = i - 73728;
    float inv = bn_g[co] * rsqrtf(bn_var[co] + 1e-5f);
    ws[OFF_BIAS2 + co] = (conv_b[co] - bn_mean[co]) * inv + bn_b[co];
  } else if (i < 77952) {
    int j = i - 73856;
    ws[OFF_A2 + j] = -__expf(A_log[j]) * L2E;
  } else if (i < 159872) {
    // wcomp[n][k], n in [0,320)
    int j = i - 77952;
    int n = j >> 8, k = j & 255;
    float v = 0.f;
    if (n < 256) {
#pragma unroll
      for (int r = 0; r < 8; ++r)
        v = fmaf(dtw[n * 8 + r], xproj_w[r * 256 + k], v);
    } else if (n < 288) {
      v = xproj_w[(8 + n - 256) * 256 + k];
    }
    ((unsigned short*)(ws + OFF_WCMP))[j] = f2bf(v);
  } else if (i < 225408) {
    int j = i - 159872;                                  // [512e][128k]
    ((unsigned short*)(ws + OFF_INWBF))[j] = f2bf(in_w[j]);
  } else if (i < 258176) {
    int j = i - 225408;                                  // [128cc][256e]
    ((unsigned short*)(ws + OFF_OUTWBF))[j] = f2bf(out_w[j]);
  }
}

// =============== K0b: transpose x -> xt[b][iy][ix][ci] bf16 ===============
__global__ __launch_bounds__(256) void k0b_transpose(
    const float* __restrict__ x, unsigned short* __restrict__ xt) {
  __shared__ float t[64][65];
  const int tid = threadIdx.x;
  const int ixh = blockIdx.x & 1;
  const int iy = (blockIdx.x >> 1) & 127;
  const int b = blockIdx.x >> 8;
  {
    const int ixl = tid & 63, cw = tid >> 6;
#pragma unroll 4
    for (int i = 0; i < 16; ++i) {
      int ci = cw * 16 + i;
      t[ci][ixl] = x[(((size_t)(b * 64 + ci) * 128) + iy) * 128 + ixh * 64 + ixl];
    }
  }
  __syncthreads();
  {
    const int cil = tid & 63, iw = tid >> 6;
    unsigned short* dst = xt + (((size_t)(b * 128 + iy) * 128) + ixh * 64) * 64;
#pragma unroll 4
    for (int i = 0; i < 16; ++i) {
      int ix = iw * 16 + i;
      dst[ix * 64 + cil] = f2bf(t[cil][ix]);
    }
  }
}

// =============== K1: conv3x3 s2 + BN + GELU via bf16 MFMA; emits ydsr bf16 + ydsbf ===============
__global__ __launch_bounds__(256) void k1_conv_mfma(
    const unsigned short* __restrict__ xt, const unsigned short* __restrict__ wbf,
    const float* __restrict__ bias2, unsigned short* __restrict__ ydsr,
    unsigned short* __restrict__ ydsbf) {
  __shared__ unsigned short ldt[64][66];
  const int tid = threadIdx.x;
  const int lane = tid & 63;
  const int w = tid >> 6;
  const int col = lane & 15, quad = lane >> 4;
  const int cohalf = blockIdx.x & 1;
  const int oy = (blockIdx.x >> 1) & 63;
  const int b = blockIdx.x >> 7;
  const int co0 = cohalf * 64 + (w & 1) * 32;
  const int tok0 = (w >> 1) * 32;
  const int iy0 = 2 * oy - 1;
  const bh8 bzero = {};
  f4v acc[2][2];
#pragma unroll
  for (int mt = 0; mt < 2; ++mt)
#pragma unroll
    for (int nt = 0; nt < 2; ++nt) acc[mt][nt] = (f4v){0.f, 0.f, 0.f, 0.f};

  const unsigned short* ap0 = wbf + (size_t)(co0 + col) * 576;
  const unsigned short* ap1 = wbf + (size_t)(co0 + 16 + col) * 576;

  for (int tap = 0; tap < 9; ++tap) {
    const int kh = tap / 3, kw = tap - kh * 3;
    const int iy = iy0 + kh;
    const int ix0 = 2 * (tok0 + col) - 1 + kw;
    const int ix1 = ix0 + 32;
    const unsigned short* xrow = xt + (long)(b * 128 + iy) * 8192;
    const bool ok0 = (iy >= 0) && (ix0 >= 0);
    const bool ok1 = (iy >= 0);
#pragma unroll
    for (int kc = 0; kc < 2; ++kc) {
      const int cib = kc * 32 + quad * 8;
      bh8 a0 = *(const bh8*)&ap0[tap * 64 + cib];
      bh8 a1 = *(const bh8*)&ap1[tap * 64 + cib];
      bh8 b0 = *(const bh8*)&xrow[(long)ix0 * 64 + cib];
      bh8 b1 = *(const bh8*)&xrow[(long)ix1 * 64 + cib];
      if (!ok0) b0 = bzero;
      if (!ok1) b1 = bzero;
      acc[0][0] = __builtin_amdgcn_mfma_f32_16x16x32_bf16(a0, b0, acc[0][0], 0, 0, 0);
      acc[1][0] = __builtin_amdgcn_mfma_f32_16x16x32_bf16(a1, b0, acc[1][0], 0, 0, 0);
      acc[0][1] = __builtin_amdgcn_mfma_f32_16x16x32_bf16(a0, b1, acc[0][1], 0, 0, 0);
      acc[1][1] = __builtin_amdgcn_mfma_f32_16x16x32_bf16(a1, b1, acc[1][1], 0, 0, 0);
    }
  }
#pragma unroll
  for (int mt = 0; mt < 2; ++mt)
#pragma unroll
    for (int nt = 0; nt < 2; ++nt) {
      const int tok = tok0 + nt * 16 + col;
#pragma unroll
      for (int r = 0; r < 4; ++r) {
        const int co = co0 + mt * 16 + quad * 4 + r;
        float v = acc[mt][nt][r] + bias2[co];
        float g = 0.5f * v * (1.f + erff(v * 0.70710678118f));
        unsigned short gb = f2bf(g);
        ydsr[(((size_t)(b * 128 + co) * 64) + oy) * 64 + tok] = gb;
        ldt[tok][(w & 1) * 32 + mt * 16 + quad * 4 + r] = gb;
      }
    }
  __syncthreads();
  // bf16 t-major write: ydsbf[(b*4096 + oy*64 + tok)*128 + cohalf*64 + cg]
  {
    const int tok = tid >> 2, cg = (tid & 3) * 16;
    unsigned short* dst =
        ydsbf + ((size_t)(b * 4096 + oy * 64 + tok)) * 128 + cohalf * 64 + cg;
#pragma unroll
    for (int j = 0; j < 8; ++j)
      ((unsigned int*)dst)[j] = *(const unsigned int*)&ldt[tok][cg + 2 * j];
  }
}

// =============== K2: in_proj via bf16 MFMA -> xpre bf16, z bf16 (t-major) ===============
__global__ __launch_bounds__(256) void k2_mfma(
    const unsigned short* __restrict__ ydsbf, const unsigned short* __restrict__ inwbf,
    unsigned short* __restrict__ xpre, unsigned short* __restrict__ z) {
  const int tid = threadIdx.x;
  const int lane = tid & 63;
  const int w = tid >> 6;
  const int col = lane & 15, quad = lane >> 4;
  const int tt = blockIdx.x & 255, b = blockIdx.x >> 8;
  const int t0 = tt * 16;
  bh8 afrag[4];
  {
    const unsigned short* arow = ydsbf + (size_t)(b * 4096 + t0 + col) * 128 + quad * 8;
#pragma unroll
    for (int kb = 0; kb < 4; ++kb) afrag[kb] = *(const bh8*)&arow[kb * 32];
  }
  f4v acc[8];
#pragma unroll
  for (int j = 0; j < 8; ++j) acc[j] = (f4v){0.f, 0.f, 0.f, 0.f};
  const int nt0 = w * 8;
  const unsigned short* wb = inwbf + (size_t)(nt0 * 16 + col) * 128 + quad * 8;
#pragma unroll
  for (int kb = 0; kb < 4; ++kb) {
#pragma unroll
    for (int j = 0; j < 8; ++j) {
      bh8 bfrag = *(const bh8*)&wb[(size_t)j * 2048 + kb * 32];
      acc[j] = __builtin_amdgcn_mfma_f32_16x16x32_bf16(afrag[kb], bfrag, acc[j], 0, 0, 0);
    }
  }
#pragma unroll
  for (int j = 0; j < 8; ++j) {
    const int e = (nt0 + j) * 16 + col;
#pragma unroll
    for (int r = 0; r < 4; ++r) {
      const int t = t0 + quad * 4 + r;
      if (e < 256) xpre[((size_t)(b * 4096 + t)) * 256 + e] = f2bf(acc[j][r]);
      else z[((size_t)(b * 4096 + t)) * 256 + e - 256] = f2bf(acc[j][r]);
    }
  }
}

// =============== K4: fused conv1d+SiLU + composed x_proj/dt_proj MFMA ===============
// Block = 16 tokens = 1 scan chunk, grid 1024. Phase 1: thread=d computes causal
// conv1d(k=4)+silu from bf16 xpre (19 rows), stages xin in LDS + writes xinbf.
// Phase 2: 4 waves x 5 N-tiles of mfma over wcomp -> delta, bc, dsum.
__global__ __launch_bounds__(256) void k4_mfma(
    const unsigned short* __restrict__ wcomp, const float* __restrict__ dtb,
    const unsigned short* __restrict__ xpre, const float* __restrict__ cw1,
    const float* __restrict__ cb1, unsigned short* __restrict__ xinbf,
    unsigned short* __restrict__ delta, float* __restrict__ bc,
    float* __restrict__ dsum) {
  __shared__ unsigned short ld_xin[16][264];
  __shared__ unsigned short ld_delta[16][264];
  __shared__ float ld_bc[16][33];
  const int tid = threadIdx.x;
  const int lane = tid & 63;
  const int w = tid >> 6;
  const int col = lane & 15, quad = lane >> 4;
  const int tt = blockIdx.x & 255, b = blockIdx.x >> 8;
  const int t0 = tt * 16;

  // ---- phase 1: conv1d + silu (thread = d) ----
  {
    const int d = tid;
    float4 w4 = *(const float4*)&cw1[d * 4];
    float bias = cb1[d];
    float xw[19];
#pragma unroll
    for (int i = 0; i < 19; ++i) {
      int t = t0 - 3 + i;
      xw[i] = (t >= 0) ? bf2f(xpre[((size_t)(b * 4096 + t)) * 256 + d]) : 0.f;
    }
    unsigned short* dst = xinbf + ((size_t)(b * 4096 + t0)) * 256 + d;
#pragma unroll
    for (int i = 0; i < 16; ++i) {
      float o = bias + w4.x * xw[i] + w4.y * xw[i + 1] + w4.z * xw[i + 2] +
                w4.w * xw[i + 3];
      unsigned short us = f2bf(fast_silu(o));
      ld_xin[i][d] = us;
      dst[(size_t)i * 256] = us;
    }
  }
  __syncthreads();

  // ---- phase 2: MFMA ----
  bh8 afrag[8];
#pragma unroll
  for (int kb = 0; kb < 8; ++kb)
    afrag[kb] = *(const bh8*)&ld_xin[col][quad * 8 + kb * 32];
  f4v acc[5];
#pragma unroll
  for (int j = 0; j < 5; ++j) acc[j] = (f4v){0.f, 0.f, 0.f, 0.f};

  const int nt0 = w * 5;
  const unsigned short* wb = wcomp + (size_t)(nt0 * 16 + col) * 256 + quad * 8;
#pragma unroll
  for (int kb = 0; kb < 8; ++kb) {
#pragma unroll
    for (int j = 0; j < 5; ++j) {
      bh8 bfrag = *(const bh8*)&wb[(size_t)j * 4096 + kb * 32];
      acc[j] = __builtin_amdgcn_mfma_f32_16x16x32_bf16(afrag[kb], bfrag, acc[j], 0, 0, 0);
    }
  }
#pragma unroll
  for (int j = 0; j < 5; ++j) {
    const int n = (nt0 + j) * 16 + col;
    if (n < 256) {
      float bias = dtb[n];
#pragma unroll
      for (int r = 0; r < 4; ++r) {
        float s = acc[j][r] + bias;
        float dl = fmaxf(s, 0.f) + __logf(1.f + __expf(-fabsf(s)));  // softplus
        ld_delta[quad * 4 + r][n] = f2bf(dl);
      }
    } else if (n < 288) {
#pragma unroll
      for (int r = 0; r < 4; ++r) ld_bc[quad * 4 + r][n - 256] = acc[j][r];
    }
  }
  __syncthreads();

  // dsum for this chunk (thread = d)
  {
    float ds = 0.f;
#pragma unroll
    for (int i = 0; i < 16; ++i) ds += bf2f(ld_delta[i][tid]);
    dsum[((size_t)b * 256 + tt) * 256 + tid] = ds;
  }
  // delta out
#pragma unroll
  for (int it = 0; it < 4; ++it) {
    int idx = it * 256 + tid;
    int row = idx >> 6, d4 = (idx & 63) * 4;
    unsigned long long pk = *(const unsigned long long*)&ld_delta[row][d4];
    *(unsigned long long*)&delta[((size_t)(b * 4096 + t0 + row)) * 256 + d4] = pk;
  }
  // bc out
  if (tid < 128) {
    int row = tid >> 3, q = (tid & 7) * 4;
    float4 v = make_float4(ld_bc[row][q], ld_bc[row][q + 1],
                           ld_bc[row][q + 2], ld_bc[row][q + 3]);
    *(float4*)&bc[((size_t)(b * 4096 + t0 + row)) * 32 + q] = v;
  }
}

// =============== K5a: pass 1 -> S[b][c][n][d] chunk-local scan ===============
__global__ __launch_bounds__(256) void k5a_scan1(
    const unsigned short* __restrict__ xinbf, const float* __restrict__ bc,
    const unsigned short* __restrict__ delta, const float* __restrict__ a2tab,
    float* __restrict__ S) {
  __shared__ __align__(16) float bct[TCH * 32];
  const int tid = threadIdx.x;
  const int d = tid;
  const int c = blockIdx.x & (NCH - 1), b = blockIdx.x >> 8;
  const int t0 = c * TCH;
  {
    const float* src = bc + (size_t)(b * 4096 + t0) * 32;
    for (int i = tid; i < TCH * 32; i += 256) bct[i] = src[i];
  }
  float A2[16];
#pragma unroll
  for (int j = 0; j < 4; ++j) {
    float4 a = *(const float4*)&a2tab[d * 16 + j * 4];
    A2[4 * j + 0] = a.x; A2[4 * j + 1] = a.y; A2[4 * j + 2] = a.z; A2[4 * j + 3] = a.w;
  }
  float h[16];
#pragma unroll
  for (int n = 0; n < 16; ++n) h[n] = 0.f;
  const unsigned short* pd = delta + (size_t)(b * 4096 + t0) * 256 + d;
  const unsigned short* px = xinbf + (size_t)(b * 4096 + t0) * 256 + d;
  __syncthreads();
#pragma unroll 4
  for (int i = 0; i < TCH; ++i) {
    float dl = bf2f(pd[(size_t)i * 256]);
    float xv = bf2f(px[(size_t)i * 256]);
    float dlx = dl * xv;
    const float* r = &bct[i * 32];
    float4 B0 = *(const float4*)&r[0];
    float4 B1 = *(const float4*)&r[4];
    float4 B2 = *(const float4*)&r[8];
    float4 B3 = *(const float4*)&r[12];
    float Bv[16] = {B0.x, B0.y, B0.z, B0.w, B1.x, B1.y, B1.z, B1.w,
                    B2.x, B2.y, B2.z, B2.w, B3.x, B3.y, B3.z, B3.w};
#pragma unroll
    for (int n = 0; n < 16; ++n)
      h[n] = fmaf(exp2f(dl * A2[n]), h[n], dlx * Bv[n]);
  }
  const size_t sbase = ((size_t)(b * NCH + c) * 16) * 256 + d;
#pragma unroll
  for (int n = 0; n < 16; ++n) S[sbase + (size_t)n * 256] = h[n];
}

// =============== K5b1: within-group combine (in-place exclusive prefix) ===============
__global__ __launch_bounds__(256) void k5b1_group(
    float* __restrict__ S, const float* __restrict__ dsum,
    const float* __restrict__ a2tab, float* __restrict__ Gs,
    float* __restrict__ Gd) {
  const int d = threadIdx.x;
  const int n = blockIdx.x & 15, g = (blockIdx.x >> 4) & (NG - 1),
            b = blockIdx.x >> 8;
  const float A2 = a2tab[d * 16 + n];
  float h = 0.f, cum = 0.f;
#pragma unroll 4
  for (int c16 = 0; c16 < GSZ; ++c16) {
    int c = g * GSZ + c16;
    size_t si = ((size_t)(b * NCH + c) * 16 + n) * 256 + d;
    float s = S[si];
    float dsv = dsum[((size_t)b * NCH + c) * 256 + d];
    float P = exp2f(A2 * dsv);
    S[si] = h;
    h = fmaf(P, h, s);
    cum += dsv;
  }
  Gs[((size_t)(b * NG + g) * 16 + n) * 256 + d] = h;
  if (n == 0) Gd[((size_t)b * NG + g) * 256 + d] = cum;
}

// =============== K5b2: scan group totals -> ginit in-place over Gs ===============
__global__ __launch_bounds__(256) void k5b2_groupscan(
    float* __restrict__ Gs, const float* __restrict__ Gd,
    const float* __restrict__ a2tab) {
  const int d = threadIdx.x;
  const int n = blockIdx.x & 15, b = blockIdx.x >> 4;
  const float A2 = a2tab[d * 16 + n];
  float h = 0.f;
#pragma unroll
  for (int g = 0; g < NG; ++g) {
    size_t gi = ((size_t)(b * NG + g) * 16 + n) * 256 + d;
    float s = Gs[gi];
    float P = exp2f(A2 * Gd[((size_t)b * NG + g) * 256 + d]);
    Gs[gi] = h;
    h = fmaf(P, h, s);
  }
}

// =============== K5c: pass 2 -> yact bf16, fused (+x*Dp)*silu(z) ===============
__global__ __launch_bounds__(256) void k5c_scan2(
    const unsigned short* __restrict__ xinbf, const float* __restrict__ bc,
    const unsigned short* __restrict__ delta, const unsigned short* __restrict__ z,
    const float* __restrict__ a2tab, const float* __restrict__ Dp,
    const float* __restrict__ dsum, const float* __restrict__ Gs,
    const float* __restrict__ S, unsigned short* __restrict__ yabf) {
  __shared__ __align__(16) float bct[TCH * 32];
  const int tid = threadIdx.x;
  const int d = tid;
  const int c = blockIdx.x & (NCH - 1), b = blockIdx.x >> 8;
  const int t0 = c * TCH;
  {
    const float* src = bc + (size_t)(b * 4096 + t0) * 32;
    for (int i = tid; i < TCH * 32; i += 256) bct[i] = src[i];
  }
  float A2[16];
#pragma unroll
  for (int j = 0; j < 4; ++j) {
    float4 a = *(const float4*)&a2tab[d * 16 + j * 4];
    A2[4 * j + 0] = a.x; A2[4 * j + 1] = a.y; A2[4 * j + 2] = a.z; A2[4 * j + 3] = a.w;
  }
  const float Dpd = Dp[d];
  const int g = c >> 4, c16 = c & 15;
  float dpref = 0.f;
  {
    const float* pds = dsum + ((size_t)b * NCH + g * GSZ) * 256 + d;
    for (int cc = 0; cc < c16; ++cc) dpref += pds[(size_t)cc * 256];
  }
  const size_t sbase = ((size_t)(b * NCH + c) * 16) * 256 + d;
  const size_t gbase = ((size_t)(b * NG + g) * 16) * 256 + d;
  float h[16];
#pragma unroll
  for (int n = 0; n < 16; ++n) {
    float gi = Gs[gbase + (size_t)n * 256];
    float hl = S[sbase + (size_t)n * 256];
    h[n] = fmaf(exp2f(A2[n] * dpref), gi, hl);
  }
  const size_t base = (size_t)(b * 4096 + t0) * 256 + d;
  const unsigned short* pd = delta + base;
  const unsigned short* px = xinbf + base;
  const unsigned short* pz = z + base;
  unsigned short* py = yabf + base;
  __syncthreads();
#pragma unroll 4
  for (int i = 0; i < TCH; ++i) {
    float dl = bf2f(pd[(size_t)i * 256]);
    float xv = bf2f(px[(size_t)i * 256]);
    float zv = bf2f(pz[(size_t)i * 256]);
    float dlx = dl * xv;
    const float* r = &bct[i * 32];
    float4 B0 = *(const float4*)&r[0];
    float4 B1 = *(const float4*)&r[4];
    float4 B2 = *(const float4*)&r[8];
    float4 B3 = *(const float4*)&r[12];
    float4 C0 = *(const float4*)&r[16];
    float4 C1 = *(const float4*)&r[20];
    float4 C2 = *(const float4*)&r[24];
    float4 C3 = *(const float4*)&r[28];
    float Bv[16] = {B0.x, B0.y, B0.z, B0.w, B1.x, B1.y, B1.z, B1.w,
                    B2.x, B2.y, B2.z, B2.w, B3.x, B3.y, B3.z, B3.w};
    float Cv[16] = {C0.x, C0.y, C0.z, C0.w, C1.x, C1.y, C1.z, C1.w,
                    C2.x, C2.y, C2.z, C2.w, C3.x, C3.y, C3.z, C3.w};
    float y = 0.f;
#pragma unroll
    for (int n = 0; n < 16; ++n) {
      h[n] = fmaf(exp2f(dl * A2[n]), h[n], dlx * Bv[n]);
      y = fmaf(h[n], Cv[n], y);
    }
    py[(size_t)i * 256] = f2bf((y + xv * Dpd) * fast_silu(zv));
  }
}

// =============== K6: out_proj via bf16 MFMA + bf16 residual -> NCHW out f32 ===============
__global__ __launch_bounds__(256) void k6_mfma(
    const unsigned short* __restrict__ yabf, const unsigned short* __restrict__ outwbf,
    const unsigned short* __restrict__ ydsr, float* __restrict__ out) {
  __shared__ float ld[16][132];
  const int tid = threadIdx.x;
  const int lane = tid & 63;
  const int w = tid >> 6;
  const int col = lane & 15, quad = lane >> 4;
  const int tt = blockIdx.x & 255, b = blockIdx.x >> 8;
  const int t0 = tt * 16;
  const int oy = t0 >> 6, ox0 = t0 & 63;
  bh8 afrag[8];
  {
    const unsigned short* arow = yabf + (size_t)(b * 4096 + t0 + col) * 256 + quad * 8;
#pragma unroll
    for (int kb = 0; kb < 8; ++kb) afrag[kb] = *(const bh8*)&arow[kb * 32];
  }
  f4v acc[2];
#pragma unroll
  for (int j = 0; j < 2; ++j) acc[j] = (f4v){0.f, 0.f, 0.f, 0.f};
  const int nt0 = w * 2;
  const unsigned short* wb = outwbf + (size_t)(nt0 * 16 + col) * 256 + quad * 8;
#pragma unroll
  for (int kb = 0; kb < 8; ++kb) {
#pragma unroll
    for (int j = 0; j < 2; ++j) {
      bh8 bfrag = *(const bh8*)&wb[(size_t)j * 4096 + kb * 32];
      acc[j] = __builtin_amdgcn_mfma_f32_16x16x32_bf16(afrag[kb], bfrag, acc[j], 0, 0, 0);
    }
  }
#pragma unroll
  for (int j = 0; j < 2; ++j)
#pragma unroll
    for (int r = 0; r < 4; ++r)
      ld[quad * 4 + r][(nt0 + j) * 16 + col] = acc[j][r];
  __syncthreads();
  {
    const int cc = tid >> 1, half = tid & 1;
    size_t base = (((size_t)(b * 128 + cc) * 64) + oy) * 64 + ox0 + half * 8;
    const unsigned short* rp = ydsr + base;
    const int m0 = half * 8;
    float4 o0 = make_float4(ld[m0 + 0][cc] + bf2f(rp[0]), ld[m0 + 1][cc] + bf2f(rp[1]),
                            ld[m0 + 2][cc] + bf2f(rp[2]), ld[m0 + 3][cc] + bf2f(rp[3]));
    float4 o1 = make_float4(ld[m0 + 4][cc] + bf2f(rp[4]), ld[m0 + 5][cc] + bf2f(rp[5]),
                            ld[m0 + 6][cc] + bf2f(rp[6]), ld[m0 + 7][cc] + bf2f(rp[7]));
    *(float4*)&out[base] = o0;
    *(float4*)&out[base + 4] = o1;
  }
}

// =============== launch ===============
extern "C" void kernel_launch(void* const* d_in, const int* in_sizes, int n_in,
                              void* d_out, int out_size, void* d_ws, size_t ws_size,
                              hipStream_t stream) {
  (void)in_sizes; (void)n_in; (void)out_size; (void)ws_size;
  const float* x        = (const float*)d_in[0];
  const float* conv_w   = (const float*)d_in[1];
  const float* conv_b   = (const float*)d_in[2];
  const float* bn_g     = (const float*)d_in[3];
  const float* bn_b     = (const float*)d_in[4];
  const float* bn_mean  = (const float*)d_in[5];
  const float* bn_var   = (const float*)d_in[6];
  const float* in_w     = (const float*)d_in[7];
  const float* conv1d_w = (const float*)d_in[8];
  const float* conv1d_b = (const float*)d_in[9];
  const float* xproj_w  = (const float*)d_in[10];
  const float* dtproj_w = (const float*)d_in[11];
  const float* dtproj_b = (const float*)d_in[12];
  const float* A_log    = (const float*)d_in[13];
  const float* Dp       = (const float*)d_in[14];
  const float* out_w    = (const float*)d_in[15];
  float* ws = (float*)d_ws;
  float* out = (float*)d_out;

  k0_prep<<<1009, 256, 0, stream>>>(conv_w, conv_b, bn_g, bn_b, bn_mean, bn_var,
                                    xproj_w, A_log, dtproj_w, in_w, out_w, ws);
  k0b_transpose<<<1024, 256, 0, stream>>>(x, (unsigned short*)(ws + OFF_XT));
  k1_conv_mfma<<<512, 256, 0, stream>>>((const unsigned short*)(ws + OFF_XT),
                                        (const unsigned short*)(ws + OFF_WBF),
                                        ws + OFF_BIAS2,
                                        (unsigned short*)(ws + OFF_YDSR),
                                        (unsigned short*)(ws + OFF_YDSBF));
  k2_mfma<<<1024, 256, 0, stream>>>((const unsigned short*)(ws + OFF_YDSBF),
                                    (const unsigned short*)(ws + OFF_INWBF),
                                    (unsigned short*)(ws + OFF_XPRE),
                                    (unsigned short*)(ws + OFF_Z));
  k4_mfma<<<1024, 256, 0, stream>>>((const unsigned short*)(ws + OFF_WCMP),
                                    dtproj_b,
                                    (const unsigned short*)(ws + OFF_XPRE),
                                    conv1d_w, conv1d_b,
                                    (unsigned short*)(ws + OFF_XT),
                                    (unsigned short*)(ws + OFF_DELTA),
                                    ws + OFF_BC, ws + OFF_DSUM);
  k5a_scan1<<<1024, 256, 0, stream>>>((const unsigned short*)(ws + OFF_XT),
                                      ws + OFF_BC,
                                      (const unsigned short*)(ws + OFF_DELTA),
                                      ws + OFF_A2, ws + OFF_XPRE);
  k5b1_group<<<1024, 256, 0, stream>>>(ws + OFF_XPRE, ws + OFF_DSUM, ws + OFF_A2,
                                       ws + OFF_GS, ws + OFF_GD);
  k5b2_groupscan<<<64, 256, 0, stream>>>(ws + OFF_GS, ws + OFF_GD, ws + OFF_A2);
  k5c_scan2<<<1024, 256, 0, stream>>>((const unsigned short*)(ws + OFF_XT),
                                      ws + OFF_BC,
                                      (const unsigned short*)(ws + OFF_DELTA),
                                      (const unsigned short*)(ws + OFF_Z),
                                      ws + OFF_A2, Dp, ws + OFF_DSUM,
                                      ws + OFF_GS, ws + OFF_XPRE,
                                      (unsigned short*)(ws + OFF_YABF));
  k6_mfma<<<1024, 256, 0, stream>>>((const unsigned short*)(ws + OFF_YABF),
                                    (const unsigned short*)(ws + OFF_OUTWBF),
                                    (const unsigned short*)(ws + OFF_YDSR), out);
}